// Round 2
// 1627.157 us; speedup vs baseline: 1.3093x; 1.3093x over previous
//
#include <hip/hip_runtime.h>
#include <stdint.h>

#define NSEQ 256
#define LRES 384
#define NH   8
#define NL   (NSEQ*LRES)              // 98304 msa rows
#define SCALE 0.17677669529663687f    // 1/sqrt(32)

typedef unsigned short u16;
typedef unsigned int   u32;
typedef short bf16x8 __attribute__((ext_vector_type(8)));
typedef float f32x4  __attribute__((ext_vector_type(4)));

// ---------- bf16 helpers ----------
__device__ __forceinline__ u16 f2bf(float f) {
    u32 x = __float_as_uint(f);
    return (u16)((x + 0x7fffu + ((x >> 16) & 1u)) >> 16);
}
__device__ __forceinline__ u32 pack2(float a, float b) {
    u32 xa = __float_as_uint(a);
    u32 xb = __float_as_uint(b);
    xa = (xa + 0x7fffu + ((xa >> 16) & 1u)) >> 16;
    xb = ((xb + 0x7fffu + ((xb >> 16) & 1u)) >> 16) << 16;
    return xa | xb;
}
__device__ __forceinline__ uint4 pack8(const float f[8]) {
    uint4 r;
    r.x = pack2(f[0], f[1]); r.y = pack2(f[2], f[3]);
    r.z = pack2(f[4], f[5]); r.w = pack2(f[6], f[7]);
    return r;
}
__device__ __forceinline__ void unpack2(u32 u, float& f0, float& f1) {
    f0 = __uint_as_float((u & 0xffffu) << 16);
    f1 = __uint_as_float(u & 0xffff0000u);
}
__device__ __forceinline__ void unpack8(uint4 p, float f[8]) {
    unpack2(p.x, f[0], f[1]);
    unpack2(p.y, f[2], f[3]);
    unpack2(p.z, f[4], f[5]);
    unpack2(p.w, f[6], f[7]);
}

// ---------- wave-64 reductions ----------
__device__ __forceinline__ float wred_sum(float v) {
#pragma unroll
    for (int o = 32; o > 0; o >>= 1) v += __shfl_xor(v, o, 64);
    return v;
}
__device__ __forceinline__ float wred_max(float v) {
#pragma unroll
    for (int o = 32; o > 0; o >>= 1) v = fmaxf(v, __shfl_xor(v, o, 64));
    return v;
}

// =====================================================================
// K0: per-row LayerNorm stats of msa (fp32). 1 wave/row, 4 rows/blk.
// =====================================================================
__global__ __launch_bounds__(256) void rowstats_k(
    const float* __restrict__ x, float* __restrict__ stats)
{
    const int lane = threadIdx.x & 63;
    const int row = blockIdx.x * 4 + (threadIdx.x >> 6);
    const size_t base = (size_t)row * 256 + lane * 4;
    float4 v = *(const float4*)(x + base);
    float s  = wred_sum(v.x + v.y + v.z + v.w);
    float sq = wred_sum(v.x*v.x + v.y*v.y + v.z*v.z + v.w*v.w);
    if (lane == 0) {
        float mu  = s * (1.f / 256.f);
        float var = sq * (1.f / 256.f) - mu * mu;
        stats[(size_t)row * 2]     = mu;
        stats[(size_t)row * 2 + 1] = rsqrtf(var + 1e-5f);
    }
}

// =====================================================================
// K1: C(Mx256) = [LN](A)(Mx256) @ W(256x256, fp32) [+bias][epilogue]
// A is fp32 (msa) or bf16 (intermediate) per a_bf16 flag.
// tile 64x128 (blockIdx.y picks column half), 256 thr, 4x8/thr.
// =====================================================================
enum { MODE_KSW = 0, MODE_QSW = 1, MODE_QT = 2, MODE_KT = 3,
       MODE_VT = 4, MODE_GATE = 5, MODE_OUT = 6 };

__global__ __launch_bounds__(256) void gemm_ln_k(
    const void* __restrict__ Av, int a_bf16,
    const float* __restrict__ stats,
    const float* __restrict__ lng, const float* __restrict__ lnb,
    const float* __restrict__ W, const float* __restrict__ bias,
    void* __restrict__ out, const float* __restrict__ seqw, int mode)
{
    __shared__ float As_t[32][68];   // [k][row]
    __shared__ float Ws[32][132];    // [k][col]
    __shared__ float gs[256], bs[256];
    const int tid = threadIdx.x;
    const int bx = blockIdx.y;       // column half
    const int by = blockIdx.x;       // row tile
    const int tx = tid & 15, ty = tid >> 4;
    const int ar = tid >> 2, acg = tid & 3;
    const int wr = tid >> 3, wcg = tid & 7;
    const bool do_ln = (stats != nullptr);

    if (do_ln) { gs[tid] = lng[tid]; bs[tid] = lnb[tid]; }
    __syncthreads();

    const int arow_idx = by * 64 + ar;
    float mu = 0.f, rsg = 0.f;
    if (do_ln) {
        mu  = stats[(size_t)arow_idx * 2];
        rsg = stats[(size_t)arow_idx * 2 + 1];
    }

    float acc[4][8];
#pragma unroll
    for (int i = 0; i < 4; ++i)
#pragma unroll
        for (int j = 0; j < 8; ++j) acc[i][j] = 0.f;

    const size_t arow = (size_t)arow_idx * 256 + acg * 8;

    for (int kk = 0; kk < 256; kk += 32) {
        float af[8];
        if (a_bf16) {
            uint4 a8 = *(const uint4*)((const u16*)Av + arow + kk);
            unpack8(a8, af);
        } else {
            float4 x0 = *(const float4*)((const float*)Av + arow + kk);
            float4 x1 = *(const float4*)((const float*)Av + arow + kk + 4);
            af[0] = x0.x; af[1] = x0.y; af[2] = x0.z; af[3] = x0.w;
            af[4] = x1.x; af[5] = x1.y; af[6] = x1.z; af[7] = x1.w;
        }
        const float* wrow = W + (size_t)(kk + wr) * 256 + bx * 128 + wcg * 16;
        float4 w0 = *(const float4*)(wrow);
        float4 w1 = *(const float4*)(wrow + 4);
        float4 w2 = *(const float4*)(wrow + 8);
        float4 w3 = *(const float4*)(wrow + 12);
        if (do_ln) {
#pragma unroll
            for (int j = 0; j < 8; ++j) {
                const int k = kk + acg * 8 + j;
                af[j] = (af[j] - mu) * rsg * gs[k] + bs[k];
            }
        }
        __syncthreads();
#pragma unroll
        for (int j = 0; j < 8; ++j) As_t[acg * 8 + j][ar] = af[j];
        float* wsrow = &Ws[wr][wcg * 16];
        *(float4*)(wsrow)      = w0;
        *(float4*)(wsrow + 4)  = w1;
        *(float4*)(wsrow + 8)  = w2;
        *(float4*)(wsrow + 12) = w3;
        __syncthreads();
#pragma unroll 8
        for (int k = 0; k < 32; ++k) {
            const float4 a  = *(const float4*)&As_t[k][ty * 4];
            const float4 b0 = *(const float4*)&Ws[k][tx * 8];
            const float4 b1 = *(const float4*)&Ws[k][tx * 8 + 4];
            const float av[4] = {a.x, a.y, a.z, a.w};
            const float bv[8] = {b0.x, b0.y, b0.z, b0.w, b1.x, b1.y, b1.z, b1.w};
#pragma unroll
            for (int i = 0; i < 4; ++i)
#pragma unroll
                for (int j = 0; j < 8; ++j)
                    acc[i][j] = fmaf(av[i], bv[j], acc[i][j]);
        }
    }

    const int gc0 = bx * 128 + tx * 8;
    float bias8[8] = {0.f, 0.f, 0.f, 0.f, 0.f, 0.f, 0.f, 0.f};
    if (bias) {
#pragma unroll
        for (int j = 0; j < 8; ++j) bias8[j] = bias[gc0 + j];
    }

    if (mode == MODE_QSW) {
        float* o = (float*)out;
#pragma unroll
        for (int i = 0; i < 4; ++i) {
            const size_t gr = (size_t)by * 64 + ty * 4 + i;
#pragma unroll
            for (int j = 0; j < 8; ++j)
                o[gr * 256 + gc0 + j] = (acc[i][j] + bias8[j]) * SCALE;
        }
    } else if (mode == MODE_OUT) {
        // FINAL OUTPUT: fp32 (reference returns float32; d_out is float*)
        float* o = (float*)out;
#pragma unroll
        for (int i = 0; i < 4; ++i) {
            const size_t gr = (size_t)by * 64 + ty * 4 + i;
            float f[8];
#pragma unroll
            for (int j = 0; j < 8; ++j) f[j] = acc[i][j] + bias8[j];
            *(float4*)(o + gr * 256 + gc0)     = make_float4(f[0], f[1], f[2], f[3]);
            *(float4*)(o + gr * 256 + gc0 + 4) = make_float4(f[4], f[5], f[6], f[7]);
        }
    } else if (mode == MODE_KSW || mode == MODE_GATE) {
        u16* o = (u16*)out;
#pragma unroll
        for (int i = 0; i < 4; ++i) {
            const size_t gr = (size_t)by * 64 + ty * 4 + i;
            float f[8];
#pragma unroll
            for (int j = 0; j < 8; ++j) {
                float v = acc[i][j] + bias8[j];
                if (mode == MODE_GATE) v = 1.f / (1.f + __expf(-v));
                f[j] = v;
            }
            *(uint4*)(o + gr * 256 + gc0) = pack8(f);
        }
    } else if (mode == MODE_VT) {
        // V stored TRANSPOSED: vTT[h][n*32+d][ii]  (k-contig for MFMA B-op)
        u16* o = (u16*)out;
        const int h = gc0 >> 5, dlo = gc0 & 31;
        const int gr0 = by * 64 + ty * 4;            // 4 consecutive msa rows
        const int n = gr0 / LRES, ii = gr0 % LRES;   // same n for all 4 rows
        const size_t ndbase = (size_t)h * 3145728 + (size_t)(n * 32 + dlo) * 384 + ii;
#pragma unroll
        for (int j = 0; j < 8; ++j) {
            uint2 pk;
            pk.x = pack2(acc[0][j], acc[1][j]);
            pk.y = pack2(acc[2][j], acc[3][j]);
            *(uint2*)(o + ndbase + (size_t)j * 384) = pk;
        }
    } else {  // MODE_QT / MODE_KT : store to [h][i][n*32+d]
        u16* o = (u16*)out;
        const int h = gc0 >> 5, dlo = gc0 & 31;
#pragma unroll
        for (int i = 0; i < 4; ++i) {
            const int gr = by * 64 + ty * 4 + i;
            const int n = gr / LRES, ii = gr % LRES;
            float mult = (mode == MODE_QT) ? seqw[(size_t)gr * NH + h] : SCALE;
            float f[8];
#pragma unroll
            for (int j = 0; j < 8; ++j) f[j] = acc[i][j] * mult;
            *(uint4*)(o + (size_t)h * 3145728 + (size_t)ii * 8192 + n * 32 + dlo) = pack8(f);
        }
    }
}

// =====================================================================
// K2: sw_logits[(n*384+i)*8+h] = dot32(qsw[i,h*32:], ksw[n*384+i, h*32:])
// =====================================================================
__global__ __launch_bounds__(256) void swl_dot_k(
    const float* __restrict__ qsw, const u16* __restrict__ ksw,
    float* __restrict__ swl)
{
    const int gid = blockIdx.x * 256 + threadIdx.x;  // < NL*NH
    const int r = gid >> 3, h = gid & 7;
    const int i = r % LRES;
    const float* qp = qsw + (size_t)i * 256 + h * 32;
    const uint4* kp = (const uint4*)(ksw + (size_t)r * 256 + h * 32);
    float s = 0.f;
#pragma unroll
    for (int g4 = 0; g4 < 4; ++g4) {
        float kf[8]; unpack8(kp[g4], kf);
#pragma unroll
        for (int j = 0; j < 8; ++j) s += qp[g4 * 8 + j] * kf[j];
    }
    swl[gid] = s;
}

// =====================================================================
// K3: softmax over n (stride 3072) per (i,h) column. Wave per column.
// =====================================================================
__global__ __launch_bounds__(256) void softmax_n_k(float* __restrict__ swl)
{
    const int col = blockIdx.x * 4 + (threadIdx.x >> 6);  // i*8+h
    const int lane = threadIdx.x & 63;
    float* base = swl + col;
    float v[4];
#pragma unroll
    for (int t = 0; t < 4; ++t) v[t] = base[(size_t)(lane * 4 + t) * 3072];
    float mx = wred_max(fmaxf(fmaxf(v[0], v[1]), fmaxf(v[2], v[3])));
    float e[4], s = 0.f;
#pragma unroll
    for (int t = 0; t < 4; ++t) { e[t] = __expf(v[t] - mx); s += e[t]; }
    s = wred_sum(s);
    const float inv = 1.f / s;
#pragma unroll
    for (int t = 0; t < 4; ++t) base[(size_t)(lane * 4 + t) * 3072] = e[t] * inv;
}

// =====================================================================
// K4: biasH[(i*384+j)*8+h] = (LN(pair[i,j,:]) @ Wb)[h]. Wave per (i,j).
// =====================================================================
__global__ __launch_bounds__(256) void pair_bias_k(
    const float* __restrict__ pair, const float* __restrict__ g,
    const float* __restrict__ b, const float* __restrict__ Wb,
    float* __restrict__ biasH)
{
    const int lane = threadIdx.x & 63;
    const size_t rp = (size_t)blockIdx.x * 4 + (threadIdx.x >> 6);
    float2 u = *(const float2*)(pair + rp * 128 + lane * 2);
    float f0 = u.x, f1 = u.y;
    float s  = wred_sum(f0 + f1);
    float sq = wred_sum(f0 * f0 + f1 * f1);
    float mu  = s * (1.f / 128.f);
    float var = sq * (1.f / 128.f) - mu * mu;
    float rs  = rsqrtf(var + 1e-5f);
    const int c0 = lane * 2;
    float xn0 = (f0 - mu) * rs * g[c0]     + b[c0];
    float xn1 = (f1 - mu) * rs * g[c0 + 1] + b[c0 + 1];
    float4 wa0 = *(const float4*)(Wb + (size_t)c0 * 8);
    float4 wa1 = *(const float4*)(Wb + (size_t)c0 * 8 + 4);
    float4 wb0 = *(const float4*)(Wb + (size_t)(c0 + 1) * 8);
    float4 wb1 = *(const float4*)(Wb + (size_t)(c0 + 1) * 8 + 4);
    const float wa[8] = {wa0.x, wa0.y, wa0.z, wa0.w, wa1.x, wa1.y, wa1.z, wa1.w};
    const float wb_[8] = {wb0.x, wb0.y, wb0.z, wb0.w, wb1.x, wb1.y, wb1.z, wb1.w};
    float acc[8];
#pragma unroll
    for (int h = 0; h < 8; ++h) acc[h] = wred_sum(xn0 * wa[h] + xn1 * wb_[h]);
    if (lane == 0) {
#pragma unroll
        for (int h = 0; h < 8; ++h) biasH[rp * 8 + h] = acc[h];
    }
}

// =====================================================================
// MFMA tile helpers: [128 rows][64 k] bf16 tile in LDS, XOR-swizzled.
// chunk position = (chunk ^ (row&7)); 16B chunks, 8 per row.
// 128 rows x 8 chunks = 1024 chunks; 256 thr x 4 chunks each.
// =====================================================================
__device__ __forceinline__ void stage128x64(
    const u16* __restrict__ src, size_t rowStride, u16* lds, int tid)
{
    const int row   = tid >> 1;          // 128 rows, 2 threads each
    const int cbase = (tid & 1) * 4;     // chunks {0..3} or {4..7}
#pragma unroll
    for (int ch = 0; ch < 4; ++ch) {
        const int cc = cbase + ch;
        const uint4 v = *(const uint4*)(src + (size_t)row * rowStride + cc * 8);
        *(uint4*)(lds + row * 64 + ((cc ^ (row & 7)) * 8)) = v;
    }
}

__device__ __forceinline__ bf16x8 frag_read(const u16* lds, int row, int kchunk)
{
    return *(const bf16x8*)(lds + row * 64 + ((kchunk ^ (row & 7)) * 8));
}

// =====================================================================
// K5 (MFMA): part[kc][h][i][j] = sum_{k in kc slice} Q_h[i,k]*K_h[j,k]
// NT GEMM K=8192 bf16, split-K=4. 128x128 tile, 4 waves @64x64.
// Computes D[j][i] = mfma(Kfrag, Qfrag) so reg-quad = 4 consecutive j
// -> coalesced float4 stores into part[i][j]. XCD-bijective swizzle.
// =====================================================================
__global__ __launch_bounds__(256) void gemm_logits_mfma(
    const u16* __restrict__ qT, const u16* __restrict__ kT,
    float* __restrict__ part)
{
    __shared__ u16 tQ[128 * 64];
    __shared__ u16 tK[128 * 64];

    // 288 wgs: XCD swizzle (288 % 8 == 0)
    int wg = (blockIdx.x & 7) * 36 + (blockIdx.x >> 3);
    const int gsel = wg / 9;             // h*4 + kc
    const int t    = wg % 9;
    const int h  = gsel >> 2, kc = gsel & 3;
    const int bi = t / 3, bj = t % 3;

    const u16* Q = qT + (size_t)h * 3145728 + (size_t)bi * 128 * 8192;
    const u16* K = kT + (size_t)h * 3145728 + (size_t)bj * 128 * 8192;

    const int tid  = threadIdx.x;
    const int lane = tid & 63, wid = tid >> 6;
    const int wr = wid >> 1, wc = wid & 1;     // wr: j-tile, wc: i-tile
    const int g  = lane >> 4;
    const int mrow = wr * 64 + (lane & 15);    // tileK row base (j)
    const int nrow = wc * 64 + (lane & 15);    // tileQ row base (i)

    f32x4 acc[4][4];
#pragma unroll
    for (int m = 0; m < 4; ++m)
#pragma unroll
        for (int n = 0; n < 4; ++n) {
            f32x4 z = {0.f, 0.f, 0.f, 0.f};
            acc[m][n] = z;
        }

    const int k0beg = kc * 2048, k0end = k0beg + 2048;
    for (int k0 = k0beg; k0 < k0end; k0 += 64) {
        stage128x64(Q + k0, 8192, tQ, tid);
        stage128x64(K + k0, 8192, tK, tid);
        __syncthreads();
#pragma unroll
        for (int ks = 0; ks < 2; ++ks) {
            bf16x8 kf[4], qf[4];
#pragma unroll
            for (int m = 0; m < 4; ++m) kf[m] = frag_read(tK, mrow + m * 16, ks * 4 + g);
#pragma unroll
            for (int n = 0; n < 4; ++n) qf[n] = frag_read(tQ, nrow + n * 16, ks * 4 + g);
#pragma unroll
            for (int m = 0; m < 4; ++m)
#pragma unroll
                for (int n = 0; n < 4; ++n)
                    acc[m][n] = __builtin_amdgcn_mfma_f32_16x16x32_bf16(
                        kf[m], qf[n], acc[m][n], 0, 0, 0);
        }
        __syncthreads();
    }

    float* dst = part + (size_t)kc * 1179648 + (size_t)h * 147456;
    const int gj_base = bj * 128 + wr * 64 + ((lane >> 4) << 2);
    const int gi_base = bi * 128 + wc * 64 + (lane & 15);
#pragma unroll
    for (int m = 0; m < 4; ++m)
#pragma unroll
        for (int n = 0; n < 4; ++n) {
            const int gi = gi_base + n * 16;
            const int gj = gj_base + m * 16;
            *(f32x4*)(dst + (size_t)gi * 384 + gj) = acc[m][n];
        }
}

// =====================================================================
// K6: attn[h,i,:] = softmax_j( sum_kc part[kc,h,i,:] + biasH[i,:,h] )
// =====================================================================
__global__ __launch_bounds__(256) void softmax_j_k(
    const float* __restrict__ part, const float* __restrict__ biasH,
    u16* __restrict__ attnB)
{
    const int row = blockIdx.x * 4 + (threadIdx.x >> 6);  // h*384+i
    const int lane = threadIdx.x & 63;
    const int h = row / LRES, i = row % LRES;
    const float* p = part + (size_t)h * 147456 + (size_t)i * 384;
    const float* bh = biasH + (size_t)i * 3072 + h;
    float v[6];
#pragma unroll
    for (int t = 0; t < 6; ++t) {
        const int j = t * 64 + lane;
        v[t] = p[j] + p[j + 1179648] + p[j + 2359296] + p[j + 3538944]
             + bh[(size_t)j * 8];
    }
    float mx = v[0];
#pragma unroll
    for (int t = 1; t < 6; ++t) mx = fmaxf(mx, v[t]);
    mx = wred_max(mx);
    float e[6], s = 0.f;
#pragma unroll
    for (int t = 0; t < 6; ++t) { e[t] = __expf(v[t] - mx); s += e[t]; }
    s = wred_sum(s);
    const float inv = 1.f / s;
    u16* ab = attnB + (size_t)h * 147456 + (size_t)i * 384;
#pragma unroll
    for (int t = 0; t < 6; ++t) ab[t * 64 + lane] = f2bf(e[t] * inv);
}

// =====================================================================
// K7 (MFMA): per head O_h(384x8192) = attn_h(384x384) @ V_h via
// vTT[h][nd][j] (j-contig). D[nd][i] = mfma(Vfrag, Afrag): reg-quad =
// 4 consecutive d -> packed uint2 gate-multiply stores (in place).
// 128(i) x 128(nd) tile, K=384 in 6 steps. XCD swizzle (1536 % 8 == 0).
// =====================================================================
__global__ __launch_bounds__(256) void gemm_out_mfma(
    const u16* __restrict__ attnB, const u16* __restrict__ vTT,
    u16* gate_io)
{
    __shared__ u16 tV[128 * 64];
    __shared__ u16 tA[128 * 64];

    int wg = (blockIdx.x & 7) * 192 + (blockIdx.x >> 3);
    const int h  = wg / 192;
    const int r  = wg % 192;
    const int bn = r / 3;          // nd tile (64 of 128)
    const int bi = r % 3;          // i tile (3 of 128)

    const u16* A = attnB + (size_t)h * 147456 + (size_t)bi * 128 * 384;
    const u16* V = vTT   + (size_t)h * 3145728 + (size_t)bn * 128 * 384;

    const int tid  = threadIdx.x;
    const int lane = tid & 63, wid = tid >> 6;
    const int wr = wid >> 1, wc = wid & 1;     // wr: nd-tile, wc: i-tile
    const int g  = lane >> 4;
    const int mrow = wr * 64 + (lane & 15);    // tV row base (nd)
    const int nrow = wc * 64 + (lane & 15);    // tA row base (i)

    f32x4 acc[4][4];
#pragma unroll
    for (int m = 0; m < 4; ++m)
#pragma unroll
        for (int n = 0; n < 4; ++n) {
            f32x4 z = {0.f, 0.f, 0.f, 0.f};
            acc[m][n] = z;
        }

    for (int j0 = 0; j0 < 384; j0 += 64) {
        stage128x64(V + j0, 384, tV, tid);
        stage128x64(A + j0, 384, tA, tid);
        __syncthreads();
#pragma unroll
        for (int ks = 0; ks < 2; ++ks) {
            bf16x8 vf[4], af[4];
#pragma unroll
            for (int m = 0; m < 4; ++m) vf[m] = frag_read(tV, mrow + m * 16, ks * 4 + g);
#pragma unroll
            for (int n = 0; n < 4; ++n) af[n] = frag_read(tA, nrow + n * 16, ks * 4 + g);
#pragma unroll
            for (int m = 0; m < 4; ++m)
#pragma unroll
                for (int n = 0; n < 4; ++n)
                    acc[m][n] = __builtin_amdgcn_mfma_f32_16x16x32_bf16(
                        vf[m], af[n], acc[m][n], 0, 0, 0);
        }
        __syncthreads();
    }

    // epilogue: gate multiply in place. element (h, i, nd): nd = n*32+d
    const int nd_base = bn * 128 + wr * 64 + ((lane >> 4) << 2);
    const int i_base  = bi * 128 + wc * 64 + (lane & 15);
#pragma unroll
    for (int m = 0; m < 4; ++m) {
        const int nd = nd_base + m * 16;     // 4 consecutive d via regs
        const int nseq = nd >> 5, d = nd & 31;
#pragma unroll
        for (int n = 0; n < 4; ++n) {
            const int gi = i_base + n * 16;
            const size_t addr = ((size_t)(nseq * LRES + gi)) * 256 + h * 32 + d;
            uint2 g2 = *(const uint2*)(gate_io + addr);
            float gf[4];
            unpack2(g2.x, gf[0], gf[1]);
            unpack2(g2.y, gf[2], gf[3]);
            const f32x4 a = acc[m][n];
            uint2 pk;
            pk.x = pack2(a[0] * gf[0], a[1] * gf[1]);
            pk.y = pack2(a[2] * gf[2], a[3] * gf[3]);
            *(uint2*)(gate_io + addr) = pk;
        }
    }
}

// =====================================================================
// launcher
// =====================================================================
extern "C" void kernel_launch(void* const* d_in, const int* in_sizes, int n_in,
                              void* d_out, int out_size, void* d_ws, size_t ws_size,
                              hipStream_t stream)
{
    const float* msa       = (const float*)d_in[0];
    const float* pair      = (const float*)d_in[1];
    const float* ln_msa_g  = (const float*)d_in[2];
    const float* ln_msa_b  = (const float*)d_in[3];
    const float* ln_pair_g = (const float*)d_in[4];
    const float* ln_pair_b = (const float*)d_in[5];
    const float* Wq_sw     = (const float*)d_in[6];
    const float* bq_sw     = (const float*)d_in[7];
    const float* Wk_sw     = (const float*)d_in[8];
    const float* bk_sw     = (const float*)d_in[9];
    const float* Wq        = (const float*)d_in[10];
    const float* Wk        = (const float*)d_in[11];
    const float* Wv        = (const float*)d_in[12];
    const float* Wb        = (const float*)d_in[13];
    const float* Wg        = (const float*)d_in[14];
    const float* bg        = (const float*)d_in[15];
    const float* Wo        = (const float*)d_in[16];
    const float* bo        = (const float*)d_in[17];
    float* out = (float*)d_out;   // reference output dtype: float32

    char* ws = (char*)d_ws;
    u16*   slotA  = (u16*)(ws + 0);            // 50331648 B: ksw -> qT -> vTT
    u16*   slotB  = (u16*)(ws + 50331648);     // 50331648 B: kT -> gate -> a2
    float* stats  = (float*)(ws + 100663296);  // NL*2 fp32
    float* qsw    = (float*)(ws + 101449728);  // 384x256 fp32
    float* swl    = (float*)(ws + 101842944);  // NL*8 fp32
    float* biasH  = (float*)(ws + 104988672);  // 384*384*8 fp32
    float* part   = (float*)(ws + 109707264);  // 4*8*384*384 fp32
    u16*   attnB  = (u16*)(ws + 128581632);    // 8*384*384 bf16
    // total: 130940928 B (~125 MiB)

    // 1. LN row stats of msa
    rowstats_k<<<NL / 4, 256, 0, stream>>>(msa, stats);
    // 2. ksw = LN(msa) @ Wk_sw + bk_sw  -> slotA (bf16)
    gemm_ln_k<<<dim3(NL / 64, 2), 256, 0, stream>>>(
        msa, 0, stats, ln_msa_g, ln_msa_b, Wk_sw, bk_sw, slotA, nullptr, MODE_KSW);
    // 3. qsw = (LN(msa[0]) @ Wq_sw + bq_sw) * scale  (fp32)
    gemm_ln_k<<<dim3(LRES / 64, 2), 256, 0, stream>>>(
        msa, 0, stats, ln_msa_g, ln_msa_b, Wq_sw, bq_sw, qsw, nullptr, MODE_QSW);
    // 4. sw_logits
    swl_dot_k<<<NL * NH / 256, 256, 0, stream>>>(qsw, slotA, swl);
    // 5. softmax over n -> seq_weight (in place)
    softmax_n_k<<<LRES * NH / 4, 256, 0, stream>>>(swl);
    // 6. qT = LN(msa) @ Wq, x seq_weight -> slotA (ksw dead)
    gemm_ln_k<<<dim3(NL / 64, 2), 256, 0, stream>>>(
        msa, 0, stats, ln_msa_g, ln_msa_b, Wq, nullptr, slotA, swl, MODE_QT);
    // 7. kT = LN(msa) @ Wk, x scale -> slotB
    gemm_ln_k<<<dim3(NL / 64, 2), 256, 0, stream>>>(
        msa, 0, stats, ln_msa_g, ln_msa_b, Wk, nullptr, slotB, nullptr, MODE_KT);
    // 8. pair bias
    pair_bias_k<<<LRES * LRES / 4, 256, 0, stream>>>(
        pair, ln_pair_g, ln_pair_b, Wb, biasH);
    // 9. logits split-K partials (MFMA)
    gemm_logits_mfma<<<288, 256, 0, stream>>>(slotA, slotB, part);
    // 10. softmax over j (reduce partials + bias) -> attn bf16
    softmax_j_k<<<NH * LRES / 4, 256, 0, stream>>>(part, biasH, attnB);
    // 11. vTT = (LN(msa) @ Wv)^T per head -> slotA (qT dead)
    gemm_ln_k<<<dim3(NL / 64, 2), 256, 0, stream>>>(
        msa, 0, stats, ln_msa_g, ln_msa_b, Wv, nullptr, slotA, nullptr, MODE_VT);
    // 12. gate = sigmoid(LN(msa) @ Wg + bg) -> slotB (kT dead)
    gemm_ln_k<<<dim3(NL / 64, 2), 256, 0, stream>>>(
        msa, 0, stats, ln_msa_g, ln_msa_b, Wg, bg, slotB, nullptr, MODE_GATE);
    // 13. attn @ V (MFMA), gate applied IN PLACE in slotB
    gemm_out_mfma<<<1536, 256, 0, stream>>>(attnB, slotA, slotB);
    // 14. out = a2 @ Wo + bo (no LN), A is bf16 intermediate -> fp32 out
    gemm_ln_k<<<dim3(NL / 64, 2), 256, 0, stream>>>(
        slotB, 1, nullptr, nullptr, nullptr, Wo, bo, out, nullptr, MODE_OUT);
}

// Round 3
// 700.379 us; speedup vs baseline: 3.0417x; 2.3233x over previous
//
#include <hip/hip_runtime.h>
#include <stdint.h>

#define NSEQ 256
#define LRES 384
#define NH   8
#define NL   (NSEQ*LRES)              // 98304 msa rows
#define SCALE 0.17677669529663687f    // 1/sqrt(32)

typedef unsigned short u16;
typedef unsigned int   u32;
typedef short bf16x8 __attribute__((ext_vector_type(8)));
typedef float f32x4  __attribute__((ext_vector_type(4)));

// ---------- bf16 helpers ----------
__device__ __forceinline__ u16 f2bf(float f) {
    u32 x = __float_as_uint(f);
    return (u16)((x + 0x7fffu + ((x >> 16) & 1u)) >> 16);
}
__device__ __forceinline__ u32 pack2(float a, float b) {
    u32 xa = __float_as_uint(a);
    u32 xb = __float_as_uint(b);
    xa = (xa + 0x7fffu + ((xa >> 16) & 1u)) >> 16;
    xb = ((xb + 0x7fffu + ((xb >> 16) & 1u)) >> 16) << 16;
    return xa | xb;
}
__device__ __forceinline__ uint4 pack8(const float f[8]) {
    uint4 r;
    r.x = pack2(f[0], f[1]); r.y = pack2(f[2], f[3]);
    r.z = pack2(f[4], f[5]); r.w = pack2(f[6], f[7]);
    return r;
}
__device__ __forceinline__ void unpack2(u32 u, float& f0, float& f1) {
    f0 = __uint_as_float((u & 0xffffu) << 16);
    f1 = __uint_as_float(u & 0xffff0000u);
}
__device__ __forceinline__ void unpack8(uint4 p, float f[8]) {
    unpack2(p.x, f[0], f[1]);
    unpack2(p.y, f[2], f[3]);
    unpack2(p.z, f[4], f[5]);
    unpack2(p.w, f[6], f[7]);
}

// ---------- wave-64 reductions ----------
__device__ __forceinline__ float wred_sum(float v) {
#pragma unroll
    for (int o = 32; o > 0; o >>= 1) v += __shfl_xor(v, o, 64);
    return v;
}
__device__ __forceinline__ float wred_max(float v) {
#pragma unroll
    for (int o = 32; o > 0; o >>= 1) v = fmaxf(v, __shfl_xor(v, o, 64));
    return v;
}

// =====================================================================
// K0: fused LN of msa -> bf16 lnA (98304x256), + per-row stats out.
// 1 wave/row, 4 rows/blk. Memory-bound (100 MB read, 50 MB write).
// =====================================================================
__global__ __launch_bounds__(256) void ln_msa_k(
    const float* __restrict__ x, const float* __restrict__ g,
    const float* __restrict__ b, u16* __restrict__ lnA,
    float* __restrict__ stats)
{
    const int lane = threadIdx.x & 63;
    const int row = blockIdx.x * 4 + (threadIdx.x >> 6);
    const size_t base = (size_t)row * 256 + lane * 4;
    float4 v = *(const float4*)(x + base);
    float s  = wred_sum(v.x + v.y + v.z + v.w);
    float sq = wred_sum(v.x*v.x + v.y*v.y + v.z*v.z + v.w*v.w);
    const float mu  = s * (1.f / 256.f);
    const float var = sq * (1.f / 256.f) - mu * mu;
    const float rs  = rsqrtf(var + 1e-5f);
    if (lane == 0) {
        stats[(size_t)row * 2]     = mu;
        stats[(size_t)row * 2 + 1] = rs;
    }
    float4 gg = *(const float4*)(g + lane * 4);
    float4 bb = *(const float4*)(b + lane * 4);
    float f0 = (v.x - mu) * rs * gg.x + bb.x;
    float f1 = (v.y - mu) * rs * gg.y + bb.y;
    float f2 = (v.z - mu) * rs * gg.z + bb.z;
    float f3 = (v.w - mu) * rs * gg.w + bb.w;
    uint2 pk;
    pk.x = pack2(f0, f1);
    pk.y = pack2(f2, f3);
    *(uint2*)(lnA + base) = pk;
}

// =====================================================================
// K0b: transpose+convert 6 weight matrices (256x256 fp32, [k][c]) into
// WtAll (6 x 256 x 256 bf16, [c][k]). 64x64 LDS-tiled. 96 blocks.
// =====================================================================
__global__ __launch_bounds__(256) void wconv_k(
    const float* __restrict__ W0, const float* __restrict__ W1,
    const float* __restrict__ W2, const float* __restrict__ W3,
    const float* __restrict__ W4, const float* __restrict__ W5,
    u16* __restrict__ outAll)
{
    const float* Wsrc[6] = {W0, W1, W2, W3, W4, W5};
    const int widx = blockIdx.x >> 4;
    const int tile = blockIdx.x & 15;
    const int kt = tile >> 2, ct = tile & 3;
    const float* W = Wsrc[widx];
    __shared__ float ts[64][65];
    const int r  = threadIdx.x >> 2;     // 0..63
    const int cg = threadIdx.x & 3;      // 16-col group
#pragma unroll
    for (int jj = 0; jj < 4; ++jj) {
        float4 v = *(const float4*)(W + (size_t)(kt * 64 + r) * 256
                                      + ct * 64 + cg * 16 + jj * 4);
        ts[r][cg * 16 + jj * 4 + 0] = v.x;
        ts[r][cg * 16 + jj * 4 + 1] = v.y;
        ts[r][cg * 16 + jj * 4 + 2] = v.z;
        ts[r][cg * 16 + jj * 4 + 3] = v.w;
    }
    __syncthreads();
    float lo[8], hi[8];
#pragma unroll
    for (int j = 0; j < 8; ++j) lo[j] = ts[cg * 16 + j][r];
#pragma unroll
    for (int j = 0; j < 8; ++j) hi[j] = ts[cg * 16 + 8 + j][r];
    u16* o = outAll + (size_t)widx * 65536 + (size_t)(ct * 64 + r) * 256
           + kt * 64 + cg * 16;
    *(uint4*)(o)     = pack8(lo);
    *(uint4*)(o + 8) = pack8(hi);
}

// =====================================================================
// K1 (legacy fp32 path, QSW only): C = LN(A) @ W + bias, fp32 out.
// =====================================================================
enum { MODE_QSW = 1 };

__global__ __launch_bounds__(256) void gemm_ln_k(
    const void* __restrict__ Av, int a_bf16,
    const float* __restrict__ stats,
    const float* __restrict__ lng, const float* __restrict__ lnb,
    const float* __restrict__ W, const float* __restrict__ bias,
    void* __restrict__ out, const float* __restrict__ seqw, int mode)
{
    __shared__ float As_t[32][68];   // [k][row]
    __shared__ float Ws[32][132];    // [k][col]
    __shared__ float gs[256], bs[256];
    const int tid = threadIdx.x;
    const int bx = blockIdx.y;       // column half
    const int by = blockIdx.x;       // row tile
    const int tx = tid & 15, ty = tid >> 4;
    const int ar = tid >> 2, acg = tid & 3;
    const int wr = tid >> 3, wcg = tid & 7;
    const bool do_ln = (stats != nullptr);

    if (do_ln) { gs[tid] = lng[tid]; bs[tid] = lnb[tid]; }
    __syncthreads();

    const int arow_idx = by * 64 + ar;
    float mu = 0.f, rsg = 0.f;
    if (do_ln) {
        mu  = stats[(size_t)arow_idx * 2];
        rsg = stats[(size_t)arow_idx * 2 + 1];
    }

    float acc[4][8];
#pragma unroll
    for (int i = 0; i < 4; ++i)
#pragma unroll
        for (int j = 0; j < 8; ++j) acc[i][j] = 0.f;

    const size_t arow = (size_t)arow_idx * 256 + acg * 8;

    for (int kk = 0; kk < 256; kk += 32) {
        float af[8];
        if (a_bf16) {
            uint4 a8 = *(const uint4*)((const u16*)Av + arow + kk);
            unpack8(a8, af);
        } else {
            float4 x0 = *(const float4*)((const float*)Av + arow + kk);
            float4 x1 = *(const float4*)((const float*)Av + arow + kk + 4);
            af[0] = x0.x; af[1] = x0.y; af[2] = x0.z; af[3] = x0.w;
            af[4] = x1.x; af[5] = x1.y; af[6] = x1.z; af[7] = x1.w;
        }
        const float* wrow = W + (size_t)(kk + wr) * 256 + bx * 128 + wcg * 16;
        float4 w0 = *(const float4*)(wrow);
        float4 w1 = *(const float4*)(wrow + 4);
        float4 w2 = *(const float4*)(wrow + 8);
        float4 w3 = *(const float4*)(wrow + 12);
        if (do_ln) {
#pragma unroll
            for (int j = 0; j < 8; ++j) {
                const int k = kk + acg * 8 + j;
                af[j] = (af[j] - mu) * rsg * gs[k] + bs[k];
            }
        }
        __syncthreads();
#pragma unroll
        for (int j = 0; j < 8; ++j) As_t[acg * 8 + j][ar] = af[j];
        float* wsrow = &Ws[wr][wcg * 16];
        *(float4*)(wsrow)      = w0;
        *(float4*)(wsrow + 4)  = w1;
        *(float4*)(wsrow + 8)  = w2;
        *(float4*)(wsrow + 12) = w3;
        __syncthreads();
#pragma unroll 8
        for (int k = 0; k < 32; ++k) {
            const float4 a  = *(const float4*)&As_t[k][ty * 4];
            const float4 b0 = *(const float4*)&Ws[k][tx * 8];
            const float4 b1 = *(const float4*)&Ws[k][tx * 8 + 4];
            const float av[4] = {a.x, a.y, a.z, a.w};
            const float bv[8] = {b0.x, b0.y, b0.z, b0.w, b1.x, b1.y, b1.z, b1.w};
#pragma unroll
            for (int i = 0; i < 4; ++i)
#pragma unroll
                for (int j = 0; j < 8; ++j)
                    acc[i][j] = fmaf(av[i], bv[j], acc[i][j]);
        }
    }

    const int gc0 = bx * 128 + tx * 8;
    float bias8[8] = {0.f, 0.f, 0.f, 0.f, 0.f, 0.f, 0.f, 0.f};
    if (bias) {
#pragma unroll
        for (int j = 0; j < 8; ++j) bias8[j] = bias[gc0 + j];
    }

    // MODE_QSW only
    float* o = (float*)out;
#pragma unroll
    for (int i = 0; i < 4; ++i) {
        const size_t gr = (size_t)by * 64 + ty * 4 + i;
#pragma unroll
        for (int j = 0; j < 8; ++j)
            o[gr * 256 + gc0 + j] = (acc[i][j] + bias8[j]) * SCALE;
    }
}

// =====================================================================
// K2: sw_logits[(n*384+i)*8+h] = dot32(qsw[i,h*32:], ksw[n*384+i, h*32:])
// =====================================================================
__global__ __launch_bounds__(256) void swl_dot_k(
    const float* __restrict__ qsw, const u16* __restrict__ ksw,
    float* __restrict__ swl)
{
    const int gid = blockIdx.x * 256 + threadIdx.x;  // < NL*NH
    const int r = gid >> 3, h = gid & 7;
    const int i = r % LRES;
    const float* qp = qsw + (size_t)i * 256 + h * 32;
    const uint4* kp = (const uint4*)(ksw + (size_t)r * 256 + h * 32);
    float s = 0.f;
#pragma unroll
    for (int g4 = 0; g4 < 4; ++g4) {
        float kf[8]; unpack8(kp[g4], kf);
#pragma unroll
        for (int j = 0; j < 8; ++j) s += qp[g4 * 8 + j] * kf[j];
    }
    swl[gid] = s;
}

// =====================================================================
// K3: softmax over n (stride 3072) per (i,h) column. Wave per column.
// =====================================================================
__global__ __launch_bounds__(256) void softmax_n_k(float* __restrict__ swl)
{
    const int col = blockIdx.x * 4 + (threadIdx.x >> 6);  // i*8+h
    const int lane = threadIdx.x & 63;
    float* base = swl + col;
    float v[4];
#pragma unroll
    for (int t = 0; t < 4; ++t) v[t] = base[(size_t)(lane * 4 + t) * 3072];
    float mx = wred_max(fmaxf(fmaxf(v[0], v[1]), fmaxf(v[2], v[3])));
    float e[4], s = 0.f;
#pragma unroll
    for (int t = 0; t < 4; ++t) { e[t] = __expf(v[t] - mx); s += e[t]; }
    s = wred_sum(s);
    const float inv = 1.f / s;
#pragma unroll
    for (int t = 0; t < 4; ++t) base[(size_t)(lane * 4 + t) * 3072] = e[t] * inv;
}

// =====================================================================
// K4: biasH[(i*384+j)*8+h] = (LN(pair[i,j,:]) @ Wb)[h]. Wave per (i,j).
// =====================================================================
__global__ __launch_bounds__(256) void pair_bias_k(
    const float* __restrict__ pair, const float* __restrict__ g,
    const float* __restrict__ b, const float* __restrict__ Wb,
    float* __restrict__ biasH)
{
    const int lane = threadIdx.x & 63;
    const size_t rp = (size_t)blockIdx.x * 4 + (threadIdx.x >> 6);
    float2 u = *(const float2*)(pair + rp * 128 + lane * 2);
    float f0 = u.x, f1 = u.y;
    float s  = wred_sum(f0 + f1);
    float sq = wred_sum(f0 * f0 + f1 * f1);
    float mu  = s * (1.f / 128.f);
    float var = sq * (1.f / 128.f) - mu * mu;
    float rs  = rsqrtf(var + 1e-5f);
    const int c0 = lane * 2;
    float xn0 = (f0 - mu) * rs * g[c0]     + b[c0];
    float xn1 = (f1 - mu) * rs * g[c0 + 1] + b[c0 + 1];
    float4 wa0 = *(const float4*)(Wb + (size_t)c0 * 8);
    float4 wa1 = *(const float4*)(Wb + (size_t)c0 * 8 + 4);
    float4 wb0 = *(const float4*)(Wb + (size_t)(c0 + 1) * 8);
    float4 wb1 = *(const float4*)(Wb + (size_t)(c0 + 1) * 8 + 4);
    const float wa[8] = {wa0.x, wa0.y, wa0.z, wa0.w, wa1.x, wa1.y, wa1.z, wa1.w};
    const float wb_[8] = {wb0.x, wb0.y, wb0.z, wb0.w, wb1.x, wb1.y, wb1.z, wb1.w};
    float acc[8];
#pragma unroll
    for (int h = 0; h < 8; ++h) acc[h] = wred_sum(xn0 * wa[h] + xn1 * wb_[h]);
    if (lane == 0) {
#pragma unroll
        for (int h = 0; h < 8; ++h) biasH[rp * 8 + h] = acc[h];
    }
}

// =====================================================================
// MFMA tile helpers: [128 rows][64 k] bf16 tile in LDS, XOR-swizzled.
// chunk position = (chunk ^ (row&7)); 16B chunks, 8 per row.
// 128 rows x 8 chunks = 1024 chunks; 256 thr x 4 chunks each.
// =====================================================================
__device__ __forceinline__ void stage128x64(
    const u16* __restrict__ src, size_t rowStride, u16* lds, int tid)
{
    const int row   = tid >> 1;          // 128 rows, 2 threads each
    const int cbase = (tid & 1) * 4;     // chunks {0..3} or {4..7}
#pragma unroll
    for (int ch = 0; ch < 4; ++ch) {
        const int cc = cbase + ch;
        const uint4 v = *(const uint4*)(src + (size_t)row * rowStride + cc * 8);
        *(uint4*)(lds + row * 64 + ((cc ^ (row & 7)) * 8)) = v;
    }
}

__device__ __forceinline__ bf16x8 frag_read(const u16* lds, int row, int kchunk)
{
    return *(const bf16x8*)(lds + row * 64 + ((kchunk ^ (row & 7)) * 8));
}

// =====================================================================
// K1' (MFMA): proj C(98304x256) = A(bf16) @ Wt^T, Wt is [c][k] bf16.
// 128x128 tile, 4 waves @64x64, K=256 in 4 steps.
// acc[m][n] = mfma(wfrag, afrag): D row-quad -> 4 consecutive c,
// D col (lane&15) -> r. Mode epilogues reproduce legacy layouts.
// =====================================================================
enum { PROJ_KSW = 0, PROJ_QT = 1, PROJ_KT = 2, PROJ_VT = 3,
       PROJ_GATE = 4, PROJ_OUT = 5 };

__global__ __launch_bounds__(256) void proj_mfma(
    const u16* __restrict__ A, const u16* __restrict__ Wt,
    const float* __restrict__ bias, const float* __restrict__ seqw,
    void* __restrict__ out, int mode)
{
    __shared__ u16 tA[128 * 64];
    __shared__ u16 tW[128 * 64];

    // 1536 wgs, XCD swizzle (1536 % 8 == 0); colTile fast -> A reuse in L2
    int wg = (blockIdx.x & 7) * 192 + (blockIdx.x >> 3);
    const int rowTile = wg >> 1;       // 0..767
    const int colTile = wg & 1;        // 0..1

    const int tid  = threadIdx.x;
    const int lane = tid & 63, wid = tid >> 6;
    const int wr = wid >> 1, wc = wid & 1;     // wr: c-tile, wc: r-tile
    const int g  = lane >> 4;
    const int mrow = wr * 64 + (lane & 15);    // tW row base (c)
    const int nrow = wc * 64 + (lane & 15);    // tA row base (r)

    f32x4 acc[4][4];
#pragma unroll
    for (int m = 0; m < 4; ++m)
#pragma unroll
        for (int n = 0; n < 4; ++n) {
            f32x4 z = {0.f, 0.f, 0.f, 0.f};
            acc[m][n] = z;
        }

    const u16* Ab = A  + (size_t)rowTile * 128 * 256;
    const u16* Wb = Wt + (size_t)colTile * 128 * 256;

    for (int k0 = 0; k0 < 256; k0 += 64) {
        stage128x64(Ab + k0, 256, tA, tid);
        stage128x64(Wb + k0, 256, tW, tid);
        __syncthreads();
#pragma unroll
        for (int ks = 0; ks < 2; ++ks) {
            bf16x8 wf[4], af[4];
#pragma unroll
            for (int m = 0; m < 4; ++m) wf[m] = frag_read(tW, mrow + m * 16, ks * 4 + g);
#pragma unroll
            for (int n = 0; n < 4; ++n) af[n] = frag_read(tA, nrow + n * 16, ks * 4 + g);
#pragma unroll
            for (int m = 0; m < 4; ++m)
#pragma unroll
                for (int n = 0; n < 4; ++n)
                    acc[m][n] = __builtin_amdgcn_mfma_f32_16x16x32_bf16(
                        wf[m], af[n], acc[m][n], 0, 0, 0);
        }
        __syncthreads();
    }

    const int cq0 = colTile * 128 + wr * 64 + ((lane >> 4) << 2);
    const int r0  = rowTile * 128 + wc * 64 + (lane & 15);

#pragma unroll
    for (int m = 0; m < 4; ++m) {
        const int c = cq0 + m * 16;
#pragma unroll
        for (int n = 0; n < 4; ++n) {
            const int r = r0 + n * 16;
            const f32x4 a = acc[m][n];
            if (mode == PROJ_KSW || mode == PROJ_GATE) {
                float f0 = a[0] + bias[c];
                float f1 = a[1] + bias[c + 1];
                float f2 = a[2] + bias[c + 2];
                float f3 = a[3] + bias[c + 3];
                if (mode == PROJ_GATE) {
                    f0 = 1.f / (1.f + __expf(-f0));
                    f1 = 1.f / (1.f + __expf(-f1));
                    f2 = 1.f / (1.f + __expf(-f2));
                    f3 = 1.f / (1.f + __expf(-f3));
                }
                uint2 pk;
                pk.x = pack2(f0, f1);
                pk.y = pack2(f2, f3);
                *(uint2*)((u16*)out + (size_t)r * 256 + c) = pk;
            } else if (mode == PROJ_QT || mode == PROJ_KT) {
                const int h = c >> 5, d = c & 31;
                const int n_ = r / LRES, ii = r % LRES;
                const float mult = (mode == PROJ_QT)
                    ? seqw[(size_t)r * NH + h] : SCALE;
                uint2 pk;
                pk.x = pack2(a[0] * mult, a[1] * mult);
                pk.y = pack2(a[2] * mult, a[3] * mult);
                *(uint2*)((u16*)out + (size_t)h * 3145728
                          + (size_t)ii * 8192 + n_ * 32 + d) = pk;
            } else if (mode == PROJ_VT) {
                const int h = c >> 5, d = c & 31;
                const int n_ = r / LRES, ii = r % LRES;
                u16* o = (u16*)out + (size_t)h * 3145728
                       + (size_t)(n_ * 32 + d) * 384 + ii;
                o[0]   = f2bf(a[0]);
                o[384] = f2bf(a[1]);
                o[768] = f2bf(a[2]);
                o[1152] = f2bf(a[3]);
            } else { // PROJ_OUT: fp32 + bias
                float* o = (float*)out + (size_t)r * 256 + c;
                o[0] = a[0] + bias[c];
                o[1] = a[1] + bias[c + 1];
                o[2] = a[2] + bias[c + 2];
                o[3] = a[3] + bias[c + 3];
            }
        }
    }
}

// =====================================================================
// K5 (MFMA): part[kc][h][i][j] = sum_{k in kc slice} Q_h[i,k]*K_h[j,k]
// NT GEMM K=8192 bf16, split-K=4. 128x128 tile, 4 waves @64x64.
// =====================================================================
__global__ __launch_bounds__(256) void gemm_logits_mfma(
    const u16* __restrict__ qT, const u16* __restrict__ kT,
    float* __restrict__ part)
{
    __shared__ u16 tQ[128 * 64];
    __shared__ u16 tK[128 * 64];

    // 288 wgs: XCD swizzle (288 % 8 == 0)
    int wg = (blockIdx.x & 7) * 36 + (blockIdx.x >> 3);
    const int gsel = wg / 9;             // h*4 + kc
    const int t    = wg % 9;
    const int h  = gsel >> 2, kc = gsel & 3;
    const int bi = t / 3, bj = t % 3;

    const u16* Q = qT + (size_t)h * 3145728 + (size_t)bi * 128 * 8192;
    const u16* K = kT + (size_t)h * 3145728 + (size_t)bj * 128 * 8192;

    const int tid  = threadIdx.x;
    const int lane = tid & 63, wid = tid >> 6;
    const int wr = wid >> 1, wc = wid & 1;     // wr: j-tile, wc: i-tile
    const int g  = lane >> 4;
    const int mrow = wr * 64 + (lane & 15);    // tileK row base (j)
    const int nrow = wc * 64 + (lane & 15);    // tileQ row base (i)

    f32x4 acc[4][4];
#pragma unroll
    for (int m = 0; m < 4; ++m)
#pragma unroll
        for (int n = 0; n < 4; ++n) {
            f32x4 z = {0.f, 0.f, 0.f, 0.f};
            acc[m][n] = z;
        }

    const int k0beg = kc * 2048, k0end = k0beg + 2048;
    for (int k0 = k0beg; k0 < k0end; k0 += 64) {
        stage128x64(Q + k0, 8192, tQ, tid);
        stage128x64(K + k0, 8192, tK, tid);
        __syncthreads();
#pragma unroll
        for (int ks = 0; ks < 2; ++ks) {
            bf16x8 kf[4], qf[4];
#pragma unroll
            for (int m = 0; m < 4; ++m) kf[m] = frag_read(tK, mrow + m * 16, ks * 4 + g);
#pragma unroll
            for (int n = 0; n < 4; ++n) qf[n] = frag_read(tQ, nrow + n * 16, ks * 4 + g);
#pragma unroll
            for (int m = 0; m < 4; ++m)
#pragma unroll
                for (int n = 0; n < 4; ++n)
                    acc[m][n] = __builtin_amdgcn_mfma_f32_16x16x32_bf16(
                        kf[m], qf[n], acc[m][n], 0, 0, 0);
        }
        __syncthreads();
    }

    float* dst = part + (size_t)kc * 1179648 + (size_t)h * 147456;
    const int gj_base = bj * 128 + wr * 64 + ((lane >> 4) << 2);
    const int gi_base = bi * 128 + wc * 64 + (lane & 15);
#pragma unroll
    for (int m = 0; m < 4; ++m)
#pragma unroll
        for (int n = 0; n < 4; ++n) {
            const int gi = gi_base + n * 16;
            const int gj = gj_base + m * 16;
            *(f32x4*)(dst + (size_t)gi * 384 + gj) = acc[m][n];
        }
}

// =====================================================================
// K6: attn[h,i,:] = softmax_j( sum_kc part[kc,h,i,:] + biasH[i,:,h] )
// =====================================================================
__global__ __launch_bounds__(256) void softmax_j_k(
    const float* __restrict__ part, const float* __restrict__ biasH,
    u16* __restrict__ attnB)
{
    const int row = blockIdx.x * 4 + (threadIdx.x >> 6);  // h*384+i
    const int lane = threadIdx.x & 63;
    const int h = row / LRES, i = row % LRES;
    const float* p = part + (size_t)h * 147456 + (size_t)i * 384;
    const float* bh = biasH + (size_t)i * 3072 + h;
    float v[6];
#pragma unroll
    for (int t = 0; t < 6; ++t) {
        const int j = t * 64 + lane;
        v[t] = p[j] + p[j + 1179648] + p[j + 2359296] + p[j + 3538944]
             + bh[(size_t)j * 8];
    }
    float mx = v[0];
#pragma unroll
    for (int t = 1; t < 6; ++t) mx = fmaxf(mx, v[t]);
    mx = wred_max(mx);
    float e[6], s = 0.f;
#pragma unroll
    for (int t = 0; t < 6; ++t) { e[t] = __expf(v[t] - mx); s += e[t]; }
    s = wred_sum(s);
    const float inv = 1.f / s;
    u16* ab = attnB + (size_t)h * 147456 + (size_t)i * 384;
#pragma unroll
    for (int t = 0; t < 6; ++t) ab[t * 64 + lane] = f2bf(e[t] * inv);
}

// =====================================================================
// K7 (MFMA): per head O_h(384x8192) = attn_h(384x384) @ V_h via
// vTT[h][nd][j] (j-contig). Gate applied IN PLACE.
// =====================================================================
__global__ __launch_bounds__(256) void gemm_out_mfma(
    const u16* __restrict__ attnB, const u16* __restrict__ vTT,
    u16* gate_io)
{
    __shared__ u16 tV[128 * 64];
    __shared__ u16 tA[128 * 64];

    int wg = (blockIdx.x & 7) * 192 + (blockIdx.x >> 3);
    const int h  = wg / 192;
    const int r  = wg % 192;
    const int bn = r / 3;          // nd tile (64 of 128)
    const int bi = r % 3;          // i tile (3 of 128)

    const u16* A = attnB + (size_t)h * 147456 + (size_t)bi * 128 * 384;
    const u16* V = vTT   + (size_t)h * 3145728 + (size_t)bn * 128 * 384;

    const int tid  = threadIdx.x;
    const int lane = tid & 63, wid = tid >> 6;
    const int wr = wid >> 1, wc = wid & 1;     // wr: nd-tile, wc: i-tile
    const int g  = lane >> 4;
    const int mrow = wr * 64 + (lane & 15);    // tV row base (nd)
    const int nrow = wc * 64 + (lane & 15);    // tA row base (i)

    f32x4 acc[4][4];
#pragma unroll
    for (int m = 0; m < 4; ++m)
#pragma unroll
        for (int n = 0; n < 4; ++n) {
            f32x4 z = {0.f, 0.f, 0.f, 0.f};
            acc[m][n] = z;
        }

    for (int j0 = 0; j0 < 384; j0 += 64) {
        stage128x64(V + j0, 384, tV, tid);
        stage128x64(A + j0, 384, tA, tid);
        __syncthreads();
#pragma unroll
        for (int ks = 0; ks < 2; ++ks) {
            bf16x8 vf[4], af[4];
#pragma unroll
            for (int m = 0; m < 4; ++m) vf[m] = frag_read(tV, mrow + m * 16, ks * 4 + g);
#pragma unroll
            for (int n = 0; n < 4; ++n) af[n] = frag_read(tA, nrow + n * 16, ks * 4 + g);
#pragma unroll
            for (int m = 0; m < 4; ++m)
#pragma unroll
                for (int n = 0; n < 4; ++n)
                    acc[m][n] = __builtin_amdgcn_mfma_f32_16x16x32_bf16(
                        vf[m], af[n], acc[m][n], 0, 0, 0);
        }
        __syncthreads();
    }

    // epilogue: gate multiply in place. element (h, i, nd): nd = n*32+d
    const int nd_base = bn * 128 + wr * 64 + ((lane >> 4) << 2);
    const int i_base  = bi * 128 + wc * 64 + (lane & 15);
#pragma unroll
    for (int m = 0; m < 4; ++m) {
        const int nd = nd_base + m * 16;     // 4 consecutive d via regs
        const int nseq = nd >> 5, d = nd & 31;
#pragma unroll
        for (int n = 0; n < 4; ++n) {
            const int gi = i_base + n * 16;
            const size_t addr = ((size_t)(nseq * LRES + gi)) * 256 + h * 32 + d;
            uint2 g2 = *(const uint2*)(gate_io + addr);
            float gf[4];
            unpack2(g2.x, gf[0], gf[1]);
            unpack2(g2.y, gf[2], gf[3]);
            const f32x4 a = acc[m][n];
            uint2 pk;
            pk.x = pack2(a[0] * gf[0], a[1] * gf[1]);
            pk.y = pack2(a[2] * gf[2], a[3] * gf[3]);
            *(uint2*)(gate_io + addr) = pk;
        }
    }
}

// =====================================================================
// launcher
// =====================================================================
extern "C" void kernel_launch(void* const* d_in, const int* in_sizes, int n_in,
                              void* d_out, int out_size, void* d_ws, size_t ws_size,
                              hipStream_t stream)
{
    const float* msa       = (const float*)d_in[0];
    const float* pair      = (const float*)d_in[1];
    const float* ln_msa_g  = (const float*)d_in[2];
    const float* ln_msa_b  = (const float*)d_in[3];
    const float* ln_pair_g = (const float*)d_in[4];
    const float* ln_pair_b = (const float*)d_in[5];
    const float* Wq_sw     = (const float*)d_in[6];
    const float* bq_sw     = (const float*)d_in[7];
    const float* Wk_sw     = (const float*)d_in[8];
    const float* bk_sw     = (const float*)d_in[9];
    const float* Wq        = (const float*)d_in[10];
    const float* Wk        = (const float*)d_in[11];
    const float* Wv        = (const float*)d_in[12];
    const float* Wb        = (const float*)d_in[13];
    const float* Wg        = (const float*)d_in[14];
    const float* bg        = (const float*)d_in[15];
    const float* Wo        = (const float*)d_in[16];
    const float* bo        = (const float*)d_in[17];
    float* out = (float*)d_out;   // reference output dtype: float32

    char* ws = (char*)d_ws;
    u16*   slotA  = (u16*)(ws + 0);            // 50331648 B: ksw -> qT -> vTT
    u16*   slotB  = (u16*)(ws + 50331648);     // 50331648 B: kT -> gate -> a2
    float* stats  = (float*)(ws + 100663296);  // NL*2 fp32
    float* qsw    = (float*)(ws + 101449728);  // 384x256 fp32
    float* swl    = (float*)(ws + 101842944);  // NL*8 fp32
    float* biasH  = (float*)(ws + 104988672);  // 384*384*8 fp32
    float* part   = (float*)(ws + 109707264);  // 4*8*384*384 fp32
    u16*   attnB  = (u16*)(ws + 128581632);    // 8*384*384 bf16
    u16*   lnA    = (u16*)(ws + 130940928);    // NL*256 bf16 = 50331648 B
    u16*   WtAll  = (u16*)(ws + 181272576);    // 6*256*256 bf16 = 786432 B
    // total: 182059008 B (~174 MiB)

    u16* Wt_ksw = WtAll;
    u16* Wt_q   = WtAll + 65536;
    u16* Wt_k   = WtAll + 131072;
    u16* Wt_v   = WtAll + 196608;
    u16* Wt_g   = WtAll + 262144;
    u16* Wt_o   = WtAll + 327680;

    // 1. LN(msa) -> bf16 lnA + stats
    ln_msa_k<<<NL / 4, 256, 0, stream>>>(msa, ln_msa_g, ln_msa_b, lnA, stats);
    // 1b. weights -> bf16 transposed
    wconv_k<<<96, 256, 0, stream>>>(Wk_sw, Wq, Wk, Wv, Wg, Wo, WtAll);
    // 2. ksw = lnA @ Wk_sw + bk_sw  -> slotA (bf16)
    proj_mfma<<<1536, 256, 0, stream>>>(lnA, Wt_ksw, bk_sw, nullptr, slotA, PROJ_KSW);
    // 3. qsw = (LN(msa[0]) @ Wq_sw + bq_sw) * scale  (fp32, legacy path)
    gemm_ln_k<<<dim3(LRES / 64, 2), 256, 0, stream>>>(
        msa, 0, stats, ln_msa_g, ln_msa_b, Wq_sw, bq_sw, qsw, nullptr, MODE_QSW);
    // 4. sw_logits
    swl_dot_k<<<NL * NH / 256, 256, 0, stream>>>(qsw, slotA, swl);
    // 5. softmax over n -> seq_weight (in place)
    softmax_n_k<<<LRES * NH / 4, 256, 0, stream>>>(swl);
    // 6. qT = lnA @ Wq, x seq_weight -> slotA (ksw dead)
    proj_mfma<<<1536, 256, 0, stream>>>(lnA, Wt_q, nullptr, swl, slotA, PROJ_QT);
    // 7. kT = lnA @ Wk, x scale -> slotB
    proj_mfma<<<1536, 256, 0, stream>>>(lnA, Wt_k, nullptr, nullptr, slotB, PROJ_KT);
    // 8. pair bias
    pair_bias_k<<<LRES * LRES / 4, 256, 0, stream>>>(
        pair, ln_pair_g, ln_pair_b, Wb, biasH);
    // 9. logits split-K partials (MFMA)
    gemm_logits_mfma<<<288, 256, 0, stream>>>(slotA, slotB, part);
    // 10. softmax over j (reduce partials + bias) -> attn bf16
    softmax_j_k<<<NH * LRES / 4, 256, 0, stream>>>(part, biasH, attnB);
    // 11. vTT = (lnA @ Wv)^T per head -> slotA (qT dead)
    proj_mfma<<<1536, 256, 0, stream>>>(lnA, Wt_v, nullptr, nullptr, slotA, PROJ_VT);
    // 12. gate = sigmoid(lnA @ Wg + bg) -> slotB (kT dead)
    proj_mfma<<<1536, 256, 0, stream>>>(lnA, Wt_g, bg, nullptr, slotB, PROJ_GATE);
    // 13. attn @ V (MFMA), gate applied IN PLACE in slotB
    gemm_out_mfma<<<1536, 256, 0, stream>>>(attnB, slotA, slotB);
    // 14. out = a2 @ Wo + bo -> fp32 out
    proj_mfma<<<1536, 256, 0, stream>>>(slotB, Wt_o, bo, nullptr, out, PROJ_OUT);
}

// Round 4
// 640.232 us; speedup vs baseline: 3.3275x; 1.0939x over previous
//
#include <hip/hip_runtime.h>
#include <stdint.h>

#define NSEQ 256
#define LRES 384
#define NH   8
#define NL   (NSEQ*LRES)              // 98304 msa rows
#define SCALE 0.17677669529663687f    // 1/sqrt(32)

typedef unsigned short u16;
typedef unsigned int   u32;
typedef short bf16x8 __attribute__((ext_vector_type(8)));
typedef float f32x4  __attribute__((ext_vector_type(4)));

// ---------- bf16 helpers ----------
__device__ __forceinline__ u16 f2bf(float f) {
    u32 x = __float_as_uint(f);
    return (u16)((x + 0x7fffu + ((x >> 16) & 1u)) >> 16);
}
__device__ __forceinline__ u32 pack2(float a, float b) {
    u32 xa = __float_as_uint(a);
    u32 xb = __float_as_uint(b);
    xa = (xa + 0x7fffu + ((xa >> 16) & 1u)) >> 16;
    xb = ((xb + 0x7fffu + ((xb >> 16) & 1u)) >> 16) << 16;
    return xa | xb;
}
__device__ __forceinline__ uint4 pack8(const float f[8]) {
    uint4 r;
    r.x = pack2(f[0], f[1]); r.y = pack2(f[2], f[3]);
    r.z = pack2(f[4], f[5]); r.w = pack2(f[6], f[7]);
    return r;
}
__device__ __forceinline__ void unpack2(u32 u, float& f0, float& f1) {
    f0 = __uint_as_float((u & 0xffffu) << 16);
    f1 = __uint_as_float(u & 0xffff0000u);
}
__device__ __forceinline__ void unpack8(uint4 p, float f[8]) {
    unpack2(p.x, f[0], f[1]);
    unpack2(p.y, f[2], f[3]);
    unpack2(p.z, f[4], f[5]);
    unpack2(p.w, f[6], f[7]);
}

// ---------- wave-64 reductions ----------
__device__ __forceinline__ float wred_sum(float v) {
#pragma unroll
    for (int o = 32; o > 0; o >>= 1) v += __shfl_xor(v, o, 64);
    return v;
}
__device__ __forceinline__ float wred_max(float v) {
#pragma unroll
    for (int o = 32; o > 0; o >>= 1) v = fmaxf(v, __shfl_xor(v, o, 64));
    return v;
}

// =====================================================================
// K0: fused LN of msa -> bf16 lnA (98304x256), + per-row stats out.
// 1 wave/row, 4 rows/blk. Memory-bound (100 MB read, 50 MB write).
// =====================================================================
__global__ __launch_bounds__(256) void ln_msa_k(
    const float* __restrict__ x, const float* __restrict__ g,
    const float* __restrict__ b, u16* __restrict__ lnA,
    float* __restrict__ stats)
{
    const int lane = threadIdx.x & 63;
    const int row = blockIdx.x * 4 + (threadIdx.x >> 6);
    const size_t base = (size_t)row * 256 + lane * 4;
    float4 v = *(const float4*)(x + base);
    float s  = wred_sum(v.x + v.y + v.z + v.w);
    float sq = wred_sum(v.x*v.x + v.y*v.y + v.z*v.z + v.w*v.w);
    const float mu  = s * (1.f / 256.f);
    const float var = sq * (1.f / 256.f) - mu * mu;
    const float rs  = rsqrtf(var + 1e-5f);
    if (lane == 0) {
        stats[(size_t)row * 2]     = mu;
        stats[(size_t)row * 2 + 1] = rs;
    }
    float4 gg = *(const float4*)(g + lane * 4);
    float4 bb = *(const float4*)(b + lane * 4);
    float f0 = (v.x - mu) * rs * gg.x + bb.x;
    float f1 = (v.y - mu) * rs * gg.y + bb.y;
    float f2 = (v.z - mu) * rs * gg.z + bb.z;
    float f3 = (v.w - mu) * rs * gg.w + bb.w;
    uint2 pk;
    pk.x = pack2(f0, f1);
    pk.y = pack2(f2, f3);
    *(uint2*)(lnA + base) = pk;
}

// =====================================================================
// K0b: transpose+convert 6 weight matrices (256x256 fp32, [k][c]) into
// WtAll (6 x 256 x 256 bf16, [c][k]). 64x64 LDS-tiled. 96 blocks.
// =====================================================================
__global__ __launch_bounds__(256) void wconv_k(
    const float* __restrict__ W0, const float* __restrict__ W1,
    const float* __restrict__ W2, const float* __restrict__ W3,
    const float* __restrict__ W4, const float* __restrict__ W5,
    u16* __restrict__ outAll)
{
    const float* Wsrc[6] = {W0, W1, W2, W3, W4, W5};
    const int widx = blockIdx.x >> 4;
    const int tile = blockIdx.x & 15;
    const int kt = tile >> 2, ct = tile & 3;
    const float* W = Wsrc[widx];
    __shared__ float ts[64][65];
    const int r  = threadIdx.x >> 2;     // 0..63
    const int cg = threadIdx.x & 3;      // 16-col group
#pragma unroll
    for (int jj = 0; jj < 4; ++jj) {
        float4 v = *(const float4*)(W + (size_t)(kt * 64 + r) * 256
                                      + ct * 64 + cg * 16 + jj * 4);
        ts[r][cg * 16 + jj * 4 + 0] = v.x;
        ts[r][cg * 16 + jj * 4 + 1] = v.y;
        ts[r][cg * 16 + jj * 4 + 2] = v.z;
        ts[r][cg * 16 + jj * 4 + 3] = v.w;
    }
    __syncthreads();
    float lo[8], hi[8];
#pragma unroll
    for (int j = 0; j < 8; ++j) lo[j] = ts[cg * 16 + j][r];
#pragma unroll
    for (int j = 0; j < 8; ++j) hi[j] = ts[cg * 16 + 8 + j][r];
    u16* o = outAll + (size_t)widx * 65536 + (size_t)(ct * 64 + r) * 256
           + kt * 64 + cg * 16;
    *(uint4*)(o)     = pack8(lo);
    *(uint4*)(o + 8) = pack8(hi);
}

// =====================================================================
// K0c: fold ln_pair_g into Wb -> Wp[c][h] = g_c*Wb[c][h] (fp32), and
// AB[0..7] = A[h] = sum_c g_c*Wb[c][h], AB[8..15] = B[h] = sum_c b_c*Wb[c][h].
// One block, 128 threads. Tiny.
// =====================================================================
__global__ __launch_bounds__(128) void wbprep_k(
    const float* __restrict__ g, const float* __restrict__ b,
    const float* __restrict__ Wb, float* __restrict__ Wp,
    float* __restrict__ AB)
{
    __shared__ float ps[128][8];
    __shared__ float pb[128][8];
    const int c = threadIdx.x;
    const float gc = g[c], bc = b[c];
    float4 w0 = *(const float4*)(Wb + (size_t)c * 8);
    float4 w1 = *(const float4*)(Wb + (size_t)c * 8 + 4);
    const float wraw[8] = {w0.x, w0.y, w0.z, w0.w, w1.x, w1.y, w1.z, w1.w};
    float wp[8];
#pragma unroll
    for (int h = 0; h < 8; ++h) {
        wp[h] = wraw[h] * gc;
        ps[c][h] = wp[h];
        pb[c][h] = wraw[h] * bc;
    }
    *(float4*)(Wp + (size_t)c * 8)     = make_float4(wp[0], wp[1], wp[2], wp[3]);
    *(float4*)(Wp + (size_t)c * 8 + 4) = make_float4(wp[4], wp[5], wp[6], wp[7]);
    __syncthreads();
    if (c < 8) {
        float a = 0.f;
        for (int j = 0; j < 128; ++j) a += ps[j][c];
        AB[c] = a;
    } else if (c < 16) {
        const int h = c - 8;
        float a = 0.f;
        for (int j = 0; j < 128; ++j) a += pb[j][h];
        AB[8 + h] = a;
    }
}

// =====================================================================
// K1 (legacy fp32 path, QSW only): C = LN(A) @ W + bias, fp32 out.
// =====================================================================
enum { MODE_QSW = 1 };

__global__ __launch_bounds__(256) void gemm_ln_k(
    const void* __restrict__ Av, int a_bf16,
    const float* __restrict__ stats,
    const float* __restrict__ lng, const float* __restrict__ lnb,
    const float* __restrict__ W, const float* __restrict__ bias,
    void* __restrict__ out, const float* __restrict__ seqw, int mode)
{
    __shared__ float As_t[32][68];   // [k][row]
    __shared__ float Ws[32][132];    // [k][col]
    __shared__ float gs[256], bs[256];
    const int tid = threadIdx.x;
    const int bx = blockIdx.y;       // column half
    const int by = blockIdx.x;       // row tile
    const int tx = tid & 15, ty = tid >> 4;
    const int ar = tid >> 2, acg = tid & 3;
    const int wr = tid >> 3, wcg = tid & 7;
    const bool do_ln = (stats != nullptr);

    if (do_ln) { gs[tid] = lng[tid]; bs[tid] = lnb[tid]; }
    __syncthreads();

    const int arow_idx = by * 64 + ar;
    float mu = 0.f, rsg = 0.f;
    if (do_ln) {
        mu  = stats[(size_t)arow_idx * 2];
        rsg = stats[(size_t)arow_idx * 2 + 1];
    }

    float acc[4][8];
#pragma unroll
    for (int i = 0; i < 4; ++i)
#pragma unroll
        for (int j = 0; j < 8; ++j) acc[i][j] = 0.f;

    const size_t arow = (size_t)arow_idx * 256 + acg * 8;

    for (int kk = 0; kk < 256; kk += 32) {
        float af[8];
        if (a_bf16) {
            uint4 a8 = *(const uint4*)((const u16*)Av + arow + kk);
            unpack8(a8, af);
        } else {
            float4 x0 = *(const float4*)((const float*)Av + arow + kk);
            float4 x1 = *(const float4*)((const float*)Av + arow + kk + 4);
            af[0] = x0.x; af[1] = x0.y; af[2] = x0.z; af[3] = x0.w;
            af[4] = x1.x; af[5] = x1.y; af[6] = x1.z; af[7] = x1.w;
        }
        const float* wrow = W + (size_t)(kk + wr) * 256 + bx * 128 + wcg * 16;
        float4 w0 = *(const float4*)(wrow);
        float4 w1 = *(const float4*)(wrow + 4);
        float4 w2 = *(const float4*)(wrow + 8);
        float4 w3 = *(const float4*)(wrow + 12);
        if (do_ln) {
#pragma unroll
            for (int j = 0; j < 8; ++j) {
                const int k = kk + acg * 8 + j;
                af[j] = (af[j] - mu) * rsg * gs[k] + bs[k];
            }
        }
        __syncthreads();
#pragma unroll
        for (int j = 0; j < 8; ++j) As_t[acg * 8 + j][ar] = af[j];
        float* wsrow = &Ws[wr][wcg * 16];
        *(float4*)(wsrow)      = w0;
        *(float4*)(wsrow + 4)  = w1;
        *(float4*)(wsrow + 8)  = w2;
        *(float4*)(wsrow + 12) = w3;
        __syncthreads();
#pragma unroll 8
        for (int k = 0; k < 32; ++k) {
            const float4 a  = *(const float4*)&As_t[k][ty * 4];
            const float4 b0 = *(const float4*)&Ws[k][tx * 8];
            const float4 b1 = *(const float4*)&Ws[k][tx * 8 + 4];
            const float av[4] = {a.x, a.y, a.z, a.w};
            const float bv[8] = {b0.x, b0.y, b0.z, b0.w, b1.x, b1.y, b1.z, b1.w};
#pragma unroll
            for (int i = 0; i < 4; ++i)
#pragma unroll
                for (int j = 0; j < 8; ++j)
                    acc[i][j] = fmaf(av[i], bv[j], acc[i][j]);
        }
    }

    const int gc0 = bx * 128 + tx * 8;
    float bias8[8] = {0.f, 0.f, 0.f, 0.f, 0.f, 0.f, 0.f, 0.f};
    if (bias) {
#pragma unroll
        for (int j = 0; j < 8; ++j) bias8[j] = bias[gc0 + j];
    }

    // MODE_QSW only
    float* o = (float*)out;
#pragma unroll
    for (int i = 0; i < 4; ++i) {
        const size_t gr = (size_t)by * 64 + ty * 4 + i;
#pragma unroll
        for (int j = 0; j < 8; ++j)
            o[gr * 256 + gc0 + j] = (acc[i][j] + bias8[j]) * SCALE;
    }
}

// =====================================================================
// K2: sw_logits[(n*384+i)*8+h] = dot32(qsw[i,h*32:], ksw[n*384+i, h*32:])
// =====================================================================
__global__ __launch_bounds__(256) void swl_dot_k(
    const float* __restrict__ qsw, const u16* __restrict__ ksw,
    float* __restrict__ swl)
{
    const int gid = blockIdx.x * 256 + threadIdx.x;  // < NL*NH
    const int r = gid >> 3, h = gid & 7;
    const int i = r % LRES;
    const float* qp = qsw + (size_t)i * 256 + h * 32;
    const uint4* kp = (const uint4*)(ksw + (size_t)r * 256 + h * 32);
    float s = 0.f;
#pragma unroll
    for (int g4 = 0; g4 < 4; ++g4) {
        float kf[8]; unpack8(kp[g4], kf);
#pragma unroll
        for (int j = 0; j < 8; ++j) s += qp[g4 * 8 + j] * kf[j];
    }
    swl[gid] = s;
}

// =====================================================================
// K3: softmax over n (stride 3072) per (i,h) column. Wave per column.
// =====================================================================
__global__ __launch_bounds__(256) void softmax_n_k(float* __restrict__ swl)
{
    const int col = blockIdx.x * 4 + (threadIdx.x >> 6);  // i*8+h
    const int lane = threadIdx.x & 63;
    float* base = swl + col;
    float v[4];
#pragma unroll
    for (int t = 0; t < 4; ++t) v[t] = base[(size_t)(lane * 4 + t) * 3072];
    float mx = wred_max(fmaxf(fmaxf(v[0], v[1]), fmaxf(v[2], v[3])));
    float e[4], s = 0.f;
#pragma unroll
    for (int t = 0; t < 4; ++t) { e[t] = __expf(v[t] - mx); s += e[t]; }
    s = wred_sum(s);
    const float inv = 1.f / s;
#pragma unroll
    for (int t = 0; t < 4; ++t) base[(size_t)(lane * 4 + t) * 3072] = e[t] * inv;
}

// =====================================================================
// K4: biasH[(i*384+j)*8+h] = rs*dot(x, Wp[:,h]) - rs*mu*A[h] + B[h].
// 8 pairs/wave: lane = p*8+cg, lane owns 16 channels of pair p.
// 8-lane-group reductions; XOR-aligned head accumulation (acc[hh] holds
// head hh^cg -> conflict-free LDS banks + static butterfly indices).
// =====================================================================
__global__ __launch_bounds__(256) void pair_bias_k(
    const float* __restrict__ pairX, const float* __restrict__ Wp,
    const float* __restrict__ AB, float* __restrict__ biasH)
{
    __shared__ float ws[128][8];
    __shared__ float As[8], Bs[8];
    const int tid = threadIdx.x;
    {
        float4 w4 = *(const float4*)(Wp + tid * 4);
        *(float4*)(&ws[tid >> 1][(tid & 1) * 4]) = w4;
    }
    if (tid < 8)       As[tid] = AB[tid];
    else if (tid < 16) Bs[tid - 8] = AB[tid];
    __syncthreads();

    const int lane = tid & 63;
    const int p  = lane >> 3;          // pair slot within wave
    const int cg = lane & 7;           // 16-channel group
    const size_t pb = (size_t)blockIdx.x * 32 + (tid >> 6) * 8 + p;
    const float* src = pairX + pb * 128 + cg * 16;
    float x[16];
    *(float4*)(x)      = *(const float4*)(src);
    *(float4*)(x + 4)  = *(const float4*)(src + 4);
    *(float4*)(x + 8)  = *(const float4*)(src + 8);
    *(float4*)(x + 12) = *(const float4*)(src + 12);

    float s = 0.f, sq = 0.f;
#pragma unroll
    for (int j = 0; j < 16; ++j) { s += x[j]; sq += x[j] * x[j]; }
#pragma unroll
    for (int o = 1; o <= 4; o <<= 1) {
        s  += __shfl_xor(s, o, 64);
        sq += __shfl_xor(sq, o, 64);
    }
    const float mu  = s * (1.f / 128.f);
    const float var = sq * (1.f / 128.f) - mu * mu;
    const float rs  = rsqrtf(var + 1e-5f);

    // acc[hh] accumulates head (hh ^ cg): LDS bank = j*8 + (hh^cg) -> 8
    // distinct banks across cg, broadcast across p. All indices static.
    float acc[8];
#pragma unroll
    for (int hh = 0; hh < 8; ++hh) {
        const int h = hh ^ cg;
        float a = 0.f;
#pragma unroll
        for (int j = 0; j < 16; ++j) a += x[j] * ws[cg * 16 + j][h];
        acc[hh] = a;
    }
    // XOR-aligned butterfly over cg (partners' slot hh^o holds same head)
#pragma unroll
    for (int o = 1; o <= 4; o <<= 1) {
        float nv[8];
#pragma unroll
        for (int hh = 0; hh < 8; ++hh)
            nv[hh] = acc[hh] + __shfl_xor(acc[hh ^ o], o, 64);
#pragma unroll
        for (int hh = 0; hh < 8; ++hh) acc[hh] = nv[hh];
    }
    // lane's slot 0 = head cg
    const float res = rs * acc[0] - rs * mu * As[cg] + Bs[cg];
    biasH[pb * 8 + cg] = res;
}

// =====================================================================
// MFMA tile helpers: [128 rows][64 k] bf16 tile in LDS, XOR-swizzled.
// chunk position = (chunk ^ (row&7)); 16B chunks, 8 per row.
// 128 rows x 8 chunks = 1024 chunks; 256 thr x 4 chunks each.
// =====================================================================
__device__ __forceinline__ void stage128x64(
    const u16* __restrict__ src, size_t rowStride, u16* lds, int tid)
{
    const int row   = tid >> 1;          // 128 rows, 2 threads each
    const int cbase = (tid & 1) * 4;     // chunks {0..3} or {4..7}
#pragma unroll
    for (int ch = 0; ch < 4; ++ch) {
        const int cc = cbase + ch;
        const uint4 v = *(const uint4*)(src + (size_t)row * rowStride + cc * 8);
        *(uint4*)(lds + row * 64 + ((cc ^ (row & 7)) * 8)) = v;
    }
}

__device__ __forceinline__ bf16x8 frag_read(const u16* lds, int row, int kchunk)
{
    return *(const bf16x8*)(lds + row * 64 + ((kchunk ^ (row & 7)) * 8));
}

// =====================================================================
// K1' (MFMA): proj C(98304x256) = A(bf16) @ Wt^T, Wt is [c][k] bf16.
// 128x128 tile, 4 waves @64x64, K=256 in 4 steps.
// =====================================================================
enum { PROJ_KSW = 0, PROJ_QT = 1, PROJ_KT = 2, PROJ_VT = 3,
       PROJ_GATE = 4, PROJ_OUT = 5 };

__global__ __launch_bounds__(256) void proj_mfma(
    const u16* __restrict__ A, const u16* __restrict__ Wt,
    const float* __restrict__ bias, const float* __restrict__ seqw,
    void* __restrict__ out, int mode)
{
    __shared__ u16 tA[128 * 64];
    __shared__ u16 tW[128 * 64];

    // 1536 wgs, XCD swizzle (1536 % 8 == 0); colTile fast -> A reuse in L2
    int wg = (blockIdx.x & 7) * 192 + (blockIdx.x >> 3);
    const int rowTile = wg >> 1;       // 0..767
    const int colTile = wg & 1;        // 0..1

    const int tid  = threadIdx.x;
    const int lane = tid & 63, wid = tid >> 6;
    const int wr = wid >> 1, wc = wid & 1;     // wr: c-tile, wc: r-tile
    const int g  = lane >> 4;
    const int mrow = wr * 64 + (lane & 15);    // tW row base (c)
    const int nrow = wc * 64 + (lane & 15);    // tA row base (r)

    f32x4 acc[4][4];
#pragma unroll
    for (int m = 0; m < 4; ++m)
#pragma unroll
        for (int n = 0; n < 4; ++n) {
            f32x4 z = {0.f, 0.f, 0.f, 0.f};
            acc[m][n] = z;
        }

    const u16* Ab = A  + (size_t)rowTile * 128 * 256;
    const u16* Wb = Wt + (size_t)colTile * 128 * 256;

    for (int k0 = 0; k0 < 256; k0 += 64) {
        stage128x64(Ab + k0, 256, tA, tid);
        stage128x64(Wb + k0, 256, tW, tid);
        __syncthreads();
#pragma unroll
        for (int ks = 0; ks < 2; ++ks) {
            bf16x8 wf[4], af[4];
#pragma unroll
            for (int m = 0; m < 4; ++m) wf[m] = frag_read(tW, mrow + m * 16, ks * 4 + g);
#pragma unroll
            for (int n = 0; n < 4; ++n) af[n] = frag_read(tA, nrow + n * 16, ks * 4 + g);
#pragma unroll
            for (int m = 0; m < 4; ++m)
#pragma unroll
                for (int n = 0; n < 4; ++n)
                    acc[m][n] = __builtin_amdgcn_mfma_f32_16x16x32_bf16(
                        wf[m], af[n], acc[m][n], 0, 0, 0);
        }
        __syncthreads();
    }

    const int cq0 = colTile * 128 + wr * 64 + ((lane >> 4) << 2);
    const int r0  = rowTile * 128 + wc * 64 + (lane & 15);

#pragma unroll
    for (int m = 0; m < 4; ++m) {
        const int c = cq0 + m * 16;
#pragma unroll
        for (int n = 0; n < 4; ++n) {
            const int r = r0 + n * 16;
            const f32x4 a = acc[m][n];
            if (mode == PROJ_KSW || mode == PROJ_GATE) {
                float f0 = a[0] + bias[c];
                float f1 = a[1] + bias[c + 1];
                float f2 = a[2] + bias[c + 2];
                float f3 = a[3] + bias[c + 3];
                if (mode == PROJ_GATE) {
                    f0 = 1.f / (1.f + __expf(-f0));
                    f1 = 1.f / (1.f + __expf(-f1));
                    f2 = 1.f / (1.f + __expf(-f2));
                    f3 = 1.f / (1.f + __expf(-f3));
                }
                uint2 pk;
                pk.x = pack2(f0, f1);
                pk.y = pack2(f2, f3);
                *(uint2*)((u16*)out + (size_t)r * 256 + c) = pk;
            } else if (mode == PROJ_QT || mode == PROJ_KT) {
                const int h = c >> 5, d = c & 31;
                const int n_ = r / LRES, ii = r % LRES;
                const float mult = (mode == PROJ_QT)
                    ? seqw[(size_t)r * NH + h] : SCALE;
                uint2 pk;
                pk.x = pack2(a[0] * mult, a[1] * mult);
                pk.y = pack2(a[2] * mult, a[3] * mult);
                *(uint2*)((u16*)out + (size_t)h * 3145728
                          + (size_t)ii * 8192 + n_ * 32 + d) = pk;
            } else if (mode == PROJ_VT) {
                const int h = c >> 5, d = c & 31;
                const int n_ = r / LRES, ii = r % LRES;
                u16* o = (u16*)out + (size_t)h * 3145728
                       + (size_t)(n_ * 32 + d) * 384 + ii;
                o[0]   = f2bf(a[0]);
                o[384] = f2bf(a[1]);
                o[768] = f2bf(a[2]);
                o[1152] = f2bf(a[3]);
            } else { // PROJ_OUT: fp32 + bias
                float* o = (float*)out + (size_t)r * 256 + c;
                o[0] = a[0] + bias[c];
                o[1] = a[1] + bias[c + 1];
                o[2] = a[2] + bias[c + 2];
                o[3] = a[3] + bias[c + 3];
            }
        }
    }
}

// =====================================================================
// K5 (MFMA): part[kc][h][i][j] = sum_{k in kc slice} Q_h[i,k]*K_h[j,k]
// NT GEMM K=8192 bf16, split-K=4. 128x128 tile, 4 waves @64x64.
// =====================================================================
__global__ __launch_bounds__(256) void gemm_logits_mfma(
    const u16* __restrict__ qT, const u16* __restrict__ kT,
    float* __restrict__ part)
{
    __shared__ u16 tQ[128 * 64];
    __shared__ u16 tK[128 * 64];

    // 288 wgs: XCD swizzle (288 % 8 == 0)
    int wg = (blockIdx.x & 7) * 36 + (blockIdx.x >> 3);
    const int gsel = wg / 9;             // h*4 + kc
    const int t    = wg % 9;
    const int h  = gsel >> 2, kc = gsel & 3;
    const int bi = t / 3, bj = t % 3;

    const u16* Q = qT + (size_t)h * 3145728 + (size_t)bi * 128 * 8192;
    const u16* K = kT + (size_t)h * 3145728 + (size_t)bj * 128 * 8192;

    const int tid  = threadIdx.x;
    const int lane = tid & 63, wid = tid >> 6;
    const int wr = wid >> 1, wc = wid & 1;     // wr: j-tile, wc: i-tile
    const int g  = lane >> 4;
    const int mrow = wr * 64 + (lane & 15);    // tileK row base (j)
    const int nrow = wc * 64 + (lane & 15);    // tileQ row base (i)

    f32x4 acc[4][4];
#pragma unroll
    for (int m = 0; m < 4; ++m)
#pragma unroll
        for (int n = 0; n < 4; ++n) {
            f32x4 z = {0.f, 0.f, 0.f, 0.f};
            acc[m][n] = z;
        }

    const int k0beg = kc * 2048, k0end = k0beg + 2048;
    for (int k0 = k0beg; k0 < k0end; k0 += 64) {
        stage128x64(Q + k0, 8192, tQ, tid);
        stage128x64(K + k0, 8192, tK, tid);
        __syncthreads();
#pragma unroll
        for (int ks = 0; ks < 2; ++ks) {
            bf16x8 kf[4], qf[4];
#pragma unroll
            for (int m = 0; m < 4; ++m) kf[m] = frag_read(tK, mrow + m * 16, ks * 4 + g);
#pragma unroll
            for (int n = 0; n < 4; ++n) qf[n] = frag_read(tQ, nrow + n * 16, ks * 4 + g);
#pragma unroll
            for (int m = 0; m < 4; ++m)
#pragma unroll
                for (int n = 0; n < 4; ++n)
                    acc[m][n] = __builtin_amdgcn_mfma_f32_16x16x32_bf16(
                        kf[m], qf[n], acc[m][n], 0, 0, 0);
        }
        __syncthreads();
    }

    float* dst = part + (size_t)kc * 1179648 + (size_t)h * 147456;
    const int gj_base = bj * 128 + wr * 64 + ((lane >> 4) << 2);
    const int gi_base = bi * 128 + wc * 64 + (lane & 15);
#pragma unroll
    for (int m = 0; m < 4; ++m)
#pragma unroll
        for (int n = 0; n < 4; ++n) {
            const int gi = gi_base + n * 16;
            const int gj = gj_base + m * 16;
            *(f32x4*)(dst + (size_t)gi * 384 + gj) = acc[m][n];
        }
}

// =====================================================================
// K6: attn[h,i,:] = softmax_j( sum_kc part[kc,h,i,:] + biasH[i,:,h] )
// =====================================================================
__global__ __launch_bounds__(256) void softmax_j_k(
    const float* __restrict__ part, const float* __restrict__ biasH,
    u16* __restrict__ attnB)
{
    const int row = blockIdx.x * 4 + (threadIdx.x >> 6);  // h*384+i
    const int lane = threadIdx.x & 63;
    const int h = row / LRES, i = row % LRES;
    const float* p = part + (size_t)h * 147456 + (size_t)i * 384;
    const float* bh = biasH + (size_t)i * 3072 + h;
    float v[6];
#pragma unroll
    for (int t = 0; t < 6; ++t) {
        const int j = t * 64 + lane;
        v[t] = p[j] + p[j + 1179648] + p[j + 2359296] + p[j + 3538944]
             + bh[(size_t)j * 8];
    }
    float mx = v[0];
#pragma unroll
    for (int t = 1; t < 6; ++t) mx = fmaxf(mx, v[t]);
    mx = wred_max(mx);
    float e[6], s = 0.f;
#pragma unroll
    for (int t = 0; t < 6; ++t) { e[t] = __expf(v[t] - mx); s += e[t]; }
    s = wred_sum(s);
    const float inv = 1.f / s;
    u16* ab = attnB + (size_t)h * 147456 + (size_t)i * 384;
#pragma unroll
    for (int t = 0; t < 6; ++t) ab[t * 64 + lane] = f2bf(e[t] * inv);
}

// =====================================================================
// K7 (MFMA): per head O_h(384x8192) = attn_h(384x384) @ V_h via
// vTT[h][nd][j] (j-contig). Gate applied IN PLACE.
// =====================================================================
__global__ __launch_bounds__(256) void gemm_out_mfma(
    const u16* __restrict__ attnB, const u16* __restrict__ vTT,
    u16* gate_io)
{
    __shared__ u16 tV[128 * 64];
    __shared__ u16 tA[128 * 64];

    int wg = (blockIdx.x & 7) * 192 + (blockIdx.x >> 3);
    const int h  = wg / 192;
    const int r  = wg % 192;
    const int bn = r / 3;          // nd tile (64 of 128)
    const int bi = r % 3;          // i tile (3 of 128)

    const u16* A = attnB + (size_t)h * 147456 + (size_t)bi * 128 * 384;
    const u16* V = vTT   + (size_t)h * 3145728 + (size_t)bn * 128 * 384;

    const int tid  = threadIdx.x;
    const int lane = tid & 63, wid = tid >> 6;
    const int wr = wid >> 1, wc = wid & 1;     // wr: nd-tile, wc: i-tile
    const int g  = lane >> 4;
    const int mrow = wr * 64 + (lane & 15);    // tV row base (nd)
    const int nrow = wc * 64 + (lane & 15);    // tA row base (i)

    f32x4 acc[4][4];
#pragma unroll
    for (int m = 0; m < 4; ++m)
#pragma unroll
        for (int n = 0; n < 4; ++n) {
            f32x4 z = {0.f, 0.f, 0.f, 0.f};
            acc[m][n] = z;
        }

    for (int j0 = 0; j0 < 384; j0 += 64) {
        stage128x64(V + j0, 384, tV, tid);
        stage128x64(A + j0, 384, tA, tid);
        __syncthreads();
#pragma unroll
        for (int ks = 0; ks < 2; ++ks) {
            bf16x8 vf[4], af[4];
#pragma unroll
            for (int m = 0; m < 4; ++m) vf[m] = frag_read(tV, mrow + m * 16, ks * 4 + g);
#pragma unroll
            for (int n = 0; n < 4; ++n) af[n] = frag_read(tA, nrow + n * 16, ks * 4 + g);
#pragma unroll
            for (int m = 0; m < 4; ++m)
#pragma unroll
                for (int n = 0; n < 4; ++n)
                    acc[m][n] = __builtin_amdgcn_mfma_f32_16x16x32_bf16(
                        vf[m], af[n], acc[m][n], 0, 0, 0);
        }
        __syncthreads();
    }

    // epilogue: gate multiply in place. element (h, i, nd): nd = n*32+d
    const int nd_base = bn * 128 + wr * 64 + ((lane >> 4) << 2);
    const int i_base  = bi * 128 + wc * 64 + (lane & 15);
#pragma unroll
    for (int m = 0; m < 4; ++m) {
        const int nd = nd_base + m * 16;     // 4 consecutive d via regs
        const int nseq = nd >> 5, d = nd & 31;
#pragma unroll
        for (int n = 0; n < 4; ++n) {
            const int gi = i_base + n * 16;
            const size_t addr = ((size_t)(nseq * LRES + gi)) * 256 + h * 32 + d;
            uint2 g2 = *(const uint2*)(gate_io + addr);
            float gf[4];
            unpack2(g2.x, gf[0], gf[1]);
            unpack2(g2.y, gf[2], gf[3]);
            const f32x4 a = acc[m][n];
            uint2 pk;
            pk.x = pack2(a[0] * gf[0], a[1] * gf[1]);
            pk.y = pack2(a[2] * gf[2], a[3] * gf[3]);
            *(uint2*)(gate_io + addr) = pk;
        }
    }
}

// =====================================================================
// launcher
// =====================================================================
extern "C" void kernel_launch(void* const* d_in, const int* in_sizes, int n_in,
                              void* d_out, int out_size, void* d_ws, size_t ws_size,
                              hipStream_t stream)
{
    const float* msa       = (const float*)d_in[0];
    const float* pair      = (const float*)d_in[1];
    const float* ln_msa_g  = (const float*)d_in[2];
    const float* ln_msa_b  = (const float*)d_in[3];
    const float* ln_pair_g = (const float*)d_in[4];
    const float* ln_pair_b = (const float*)d_in[5];
    const float* Wq_sw     = (const float*)d_in[6];
    const float* bq_sw     = (const float*)d_in[7];
    const float* Wk_sw     = (const float*)d_in[8];
    const float* bk_sw     = (const float*)d_in[9];
    const float* Wq        = (const float*)d_in[10];
    const float* Wk        = (const float*)d_in[11];
    const float* Wv        = (const float*)d_in[12];
    const float* Wb        = (const float*)d_in[13];
    const float* Wg        = (const float*)d_in[14];
    const float* bg        = (const float*)d_in[15];
    const float* Wo        = (const float*)d_in[16];
    const float* bo        = (const float*)d_in[17];
    float* out = (float*)d_out;   // reference output dtype: float32

    char* ws = (char*)d_ws;
    u16*   slotA  = (u16*)(ws + 0);            // 50331648 B: ksw -> qT -> vTT
    u16*   slotB  = (u16*)(ws + 50331648);     // 50331648 B: kT -> gate -> a2
    float* stats  = (float*)(ws + 100663296);  // NL*2 fp32
    float* qsw    = (float*)(ws + 101449728);  // 384x256 fp32
    float* swl    = (float*)(ws + 101842944);  // NL*8 fp32
    float* biasH  = (float*)(ws + 104988672);  // 384*384*8 fp32
    float* part   = (float*)(ws + 109707264);  // 4*8*384*384 fp32
    u16*   attnB  = (u16*)(ws + 128581632);    // 8*384*384 bf16
    u16*   lnA    = (u16*)(ws + 130940928);    // NL*256 bf16 = 50331648 B
    u16*   WtAll  = (u16*)(ws + 181272576);    // 6*256*256 bf16 = 786432 B
    float* Wp     = (float*)(ws + 182059008);  // 128*8 fp32 = 4096 B
    float* AB     = (float*)(ws + 182063104);  // 16 fp32
    // total: 182063168 B (~174 MiB)

    u16* Wt_ksw = WtAll;
    u16* Wt_q   = WtAll + 65536;
    u16* Wt_k   = WtAll + 131072;
    u16* Wt_v   = WtAll + 196608;
    u16* Wt_g   = WtAll + 262144;
    u16* Wt_o   = WtAll + 327680;

    // 1. LN(msa) -> bf16 lnA + stats
    ln_msa_k<<<NL / 4, 256, 0, stream>>>(msa, ln_msa_g, ln_msa_b, lnA, stats);
    // 1b. weights -> bf16 transposed
    wconv_k<<<96, 256, 0, stream>>>(Wk_sw, Wq, Wk, Wv, Wg, Wo, WtAll);
    // 1c. pair-bias weight prep (fold ln_pair_g; A/B constants)
    wbprep_k<<<1, 128, 0, stream>>>(ln_pair_g, ln_pair_b, Wb, Wp, AB);
    // 2. ksw = lnA @ Wk_sw + bk_sw  -> slotA (bf16)
    proj_mfma<<<1536, 256, 0, stream>>>(lnA, Wt_ksw, bk_sw, nullptr, slotA, PROJ_KSW);
    // 3. qsw = (LN(msa[0]) @ Wq_sw + bq_sw) * scale  (fp32, legacy path)
    gemm_ln_k<<<dim3(LRES / 64, 2), 256, 0, stream>>>(
        msa, 0, stats, ln_msa_g, ln_msa_b, Wq_sw, bq_sw, qsw, nullptr, MODE_QSW);
    // 4. sw_logits
    swl_dot_k<<<NL * NH / 256, 256, 0, stream>>>(qsw, slotA, swl);
    // 5. softmax over n -> seq_weight (in place)
    softmax_n_k<<<LRES * NH / 4, 256, 0, stream>>>(swl);
    // 6. qT = lnA @ Wq, x seq_weight -> slotA (ksw dead)
    proj_mfma<<<1536, 256, 0, stream>>>(lnA, Wt_q, nullptr, swl, slotA, PROJ_QT);
    // 7. kT = lnA @ Wk, x scale -> slotB
    proj_mfma<<<1536, 256, 0, stream>>>(lnA, Wt_k, nullptr, nullptr, slotB, PROJ_KT);
    // 8. pair bias (memory-roofline version)
    pair_bias_k<<<LRES * LRES / 32, 256, 0, stream>>>(pair, Wp, AB, biasH);
    // 9. logits split-K partials (MFMA)
    gemm_logits_mfma<<<288, 256, 0, stream>>>(slotA, slotB, part);
    // 10. softmax over j (reduce partials + bias) -> attn bf16
    softmax_j_k<<<NH * LRES / 4, 256, 0, stream>>>(part, biasH, attnB);
    // 11. vTT = (lnA @ Wv)^T per head -> slotA (qT dead)
    proj_mfma<<<1536, 256, 0, stream>>>(lnA, Wt_v, nullptr, nullptr, slotA, PROJ_VT);
    // 12. gate = sigmoid(lnA @ Wg + bg) -> slotB (kT dead)
    proj_mfma<<<1536, 256, 0, stream>>>(lnA, Wt_g, bg, nullptr, slotB, PROJ_GATE);
    // 13. attn @ V (MFMA), gate applied IN PLACE in slotB
    gemm_out_mfma<<<1536, 256, 0, stream>>>(attnB, slotA, slotB);
    // 14. out = a2 @ Wo + bo -> fp32 out
    proj_mfma<<<1536, 256, 0, stream>>>(slotB, Wt_o, bo, nullptr, out, PROJ_OUT);
}